// Round 10
// baseline (1107.897 us; speedup 1.0000x reference)
//
#include <hip/hip_runtime.h>
#include <hip/hip_bf16.h>

namespace {
constexpr int B  = 64;
constexpr int T  = 8;
constexpr int N  = 1000;
constexpr int U  = 64;
constexpr int R  = B * N;        // 64000 rows (r = n*64 + b)
constexpr int RS = 256;          // padded K / row stride (512B rows, line-aligned)
constexpr int CSR_CAP = 65536;
}

typedef short bf16x8 __attribute__((ext_vector_type(8)));
typedef float f32x4  __attribute__((ext_vector_type(4)));
typedef unsigned short u16;

__device__ __forceinline__ float bf2f(u16 x) {
  unsigned u = ((unsigned)x) << 16;
  float f; __builtin_memcpy(&f, &u, 4); return f;
}
__device__ __forceinline__ u16 f2bf(float f) {
  unsigned u; __builtin_memcpy(&u, &f, 4);
  u += 0x7FFFu + ((u >> 16) & 1u);
  return (u16)(u >> 16);
}

// ---------------- CSR build (deterministic, no atomics) ----------------

__global__ __launch_bounds__(256) void k_count(const float* __restrict__ S,
                                               int* __restrict__ rowptr) {
  int lane = threadIdx.x & 63;
  int m = blockIdx.x * 4 + (threadIdx.x >> 6);
  int c = 0;
  for (int n = lane; n < N; n += 64) c += (S[m * N + n] != 0.f) ? 1 : 0;
  for (int off = 32; off; off >>= 1) c += __shfl_down(c, off, 64);
  if (lane == 0) rowptr[m + 1] = c;
}

__global__ __launch_bounds__(1024) void k_scan(int* __restrict__ rowptr) {
  __shared__ int sm[1024];
  int t = threadIdx.x;
  sm[t] = (t < N) ? rowptr[t + 1] : 0;
  __syncthreads();
  for (int off = 1; off < 1024; off <<= 1) {
    int v = sm[t];
    int a = (t >= off) ? sm[t - off] : 0;
    __syncthreads();
    sm[t] = v + a;
    __syncthreads();
  }
  if (t < N) rowptr[t + 1] = sm[t];
  if (t == 0) rowptr[0] = 0;
}

__global__ __launch_bounds__(256) void k_fill(const float* __restrict__ S,
                                              const int* __restrict__ rowptr,
                                              int* __restrict__ cols,
                                              float* __restrict__ vals) {
  int lane = threadIdx.x & 63;
  int m = blockIdx.x * 4 + (threadIdx.x >> 6);
  int base = rowptr[m];
  for (int n0 = 0; n0 < N; n0 += 64) {
    int n = n0 + lane;
    float v = (n < N) ? S[m * N + n] : 0.f;
    bool nz = (v != 0.f);
    unsigned long long mask = __ballot(nz);
    int pos = base + (int)__popcll(mask & ((1ull << lane) - 1ull));
    if (nz && pos < CSR_CAP) { cols[pos] = n; vals[pos] = v; }
    base += (int)__popcll(mask);
  }
}

// ---------------- inputs transpose: (B,T,N) -> Xt[t][n*64+b] fp32 ----------

__global__ __launch_bounds__(256) void k_xt(const float* __restrict__ inp,
                                            float* __restrict__ xT) {
  __shared__ float tile[64][65];
  const int t  = blockIdx.y;
  const int n0 = blockIdx.x * 64;
  const int lx = threadIdx.x & 63;
  const int ly = threadIdx.x >> 6;
  for (int bb = ly; bb < 64; bb += 4) {
    int n = n0 + lx;
    tile[bb][lx] = (n < N) ? inp[(bb * T + t) * N + n] : 0.f;
  }
  __syncthreads();
  for (int nn = ly; nn < 64; nn += 4) {
    int n = n0 + nn;
    if (n < N) xT[((size_t)t * N + n) * 64 + lx] = tile[lx][nn];
  }
}

// ---------------- scalar Chebyshev chain (fp32, all timesteps) -------------

__global__ __launch_bounds__(64) void k_sspmv(const int* __restrict__ rowptr,
                                              const int* __restrict__ cols,
                                              const float* __restrict__ vals,
                                              const float* __restrict__ in,
                                              const float* __restrict__ sub,
                                              float* __restrict__ out, int cheb) {
  const int m = blockIdx.x, b = threadIdx.x;
  const size_t toff = (size_t)blockIdx.y * R;
  float acc = 0.f;
  for (int j = rowptr[m]; j < rowptr[m + 1]; ++j)
    acc = fmaf(vals[j], in[toff + cols[j] * 64 + b], acc);
  if (cheb) acc = 2.f * acc - sub[toff + m * 64 + b];
  out[toff + m * 64 + b] = acc;
}

// ---------------- W transpose+reorder -> Wt[o][256] bf16 -------------------
// kp<192: original row ((kp&63)+1)*3 + (kp>>6);  192..194: row kp-192; else 0.

__global__ __launch_bounds__(256) void k_wprep(
    const float* __restrict__ w0, const float* __restrict__ w1,
    const float* __restrict__ w2, const float* __restrict__ w3,
    u16* __restrict__ o0, u16* __restrict__ o1,
    u16* __restrict__ o2, u16* __restrict__ o3) {
  const float* W; u16* O; int ncol;
  switch (blockIdx.y) {
    case 0:  W = w0; O = o0; ncol = 128; break;
    case 1:  W = w1; O = o1; ncol = 64;  break;
    case 2:  W = w2; O = o2; ncol = 128; break;
    default: W = w3; O = o3; ncol = 64;  break;
  }
  int idx = blockIdx.x * 256 + threadIdx.x;
  if (idx >= ncol * RS) return;
  int o = idx / RS, kp = idx - o * RS;
  float v = 0.f;
  if (kp < 192)      v = W[(((kp & 63) + 1) * 3 + (kp >> 6)) * ncol + o];
  else if (kp < 195) v = W[(kp - 192) * ncol + o];
  O[idx] = f2bf(v);
}

// ---------------- zero seg0 of A1 (initial h = 0) --------------------------

__global__ __launch_bounds__(256) void k_zseg(u16* __restrict__ A) {
  int idx = blockIdx.x * 256 + threadIdx.x;     // 512k threads
  int r = idx >> 3, q = idx & 7;
  bf16x8 z = {0, 0, 0, 0, 0, 0, 0, 0};
  *(bf16x8*)(A + (size_t)r * RS + q * 8) = z;
}

// ---------------- bf16 diffusion spmv: seg1 = S @ seg0, XCD-pinned ---------
// grid (8, 250), 256 thr = 4 waves. blockIdx.x = chunk == XCD (x-major RR).
// Wave = ONE node m (rowptr/cols/vals wave-uniform). Lane l: batch
// b = chunk*8 + (l>>3), 8 cols at cg = (l&7)*8 (16B). j-loop unrolled x8
// (8 independent loads in flight); per-acc fmaf chain stays ascending-j.
// Per-XCD working set 1MB (fits 4MB L2).
// xmode: 1 -> write scalar cols 192..194 of scA,scB from xs*; 2 -> zeros.

__global__ __launch_bounds__(256) void k_spv(
    const int* __restrict__ rowptr, const int* __restrict__ cols,
    const float* __restrict__ vals, u16* __restrict__ A,
    const float* __restrict__ xs0, const float* __restrict__ xs1,
    const float* __restrict__ xs2,
    u16* __restrict__ scA, u16* __restrict__ scB, int xmode) {
  const int chunk = blockIdx.x;
  const int m = blockIdx.y * 4 + (threadIdx.x >> 6);
  const int l = threadIdx.x & 63;
  const int b = chunk * 8 + (l >> 3);
  const int cg = (l & 7) * 8;
  const int s = rowptr[m], e = rowptr[m + 1];

  float acc[8];
#pragma unroll
  for (int i = 0; i < 8; ++i) acc[i] = 0.f;

  const u16* in = A;                            // seg0
  int j = s;
  for (; j + 7 < e; j += 8) {
    float vv[8]; bf16x8 qq[8];
#pragma unroll
    for (int u8 = 0; u8 < 8; ++u8) {
      vv[u8] = vals[j + u8];
      qq[u8] = *(const bf16x8*)(in + ((size_t)cols[j + u8] * 64 + b) * RS + cg);
    }
#pragma unroll
    for (int i = 0; i < 8; ++i) {
      float a = acc[i];
#pragma unroll
      for (int u8 = 0; u8 < 8; ++u8) a = fmaf(vv[u8], bf2f((u16)qq[u8][i]), a);
      acc[i] = a;
    }
  }
  for (; j + 3 < e; j += 4) {
    const float v0 = vals[j],     v1 = vals[j + 1];
    const float v2 = vals[j + 2], v3 = vals[j + 3];
    bf16x8 q0 = *(const bf16x8*)(in + ((size_t)cols[j]     * 64 + b) * RS + cg);
    bf16x8 q1 = *(const bf16x8*)(in + ((size_t)cols[j + 1] * 64 + b) * RS + cg);
    bf16x8 q2 = *(const bf16x8*)(in + ((size_t)cols[j + 2] * 64 + b) * RS + cg);
    bf16x8 q3 = *(const bf16x8*)(in + ((size_t)cols[j + 3] * 64 + b) * RS + cg);
#pragma unroll
    for (int i = 0; i < 8; ++i)
      acc[i] = fmaf(v3, bf2f((u16)q3[i]),
               fmaf(v2, bf2f((u16)q2[i]),
               fmaf(v1, bf2f((u16)q1[i]),
               fmaf(v0, bf2f((u16)q0[i]), acc[i]))));
  }
  for (; j < e; ++j) {
    const float v = vals[j];
    bf16x8 q = *(const bf16x8*)(in + ((size_t)cols[j] * 64 + b) * RS + cg);
#pragma unroll
    for (int i = 0; i < 8; ++i) acc[i] = fmaf(v, bf2f((u16)q[i]), acc[i]);
  }

  const size_t ro = ((size_t)m * 64 + b) * RS + 64 + cg;   // seg1
  bf16x8 o;
#pragma unroll
  for (int i = 0; i < 8; ++i) o[i] = (short)f2bf(acc[i]);
  *(bf16x8*)(A + ro) = o;

  if (xmode && (l & 7) == 0) {
    const int r = m * 64 + b;
    u16 s0v = 0, s1v = 0, s2v = 0;
    if (xmode == 1) { s0v = f2bf(xs0[r]); s1v = f2bf(xs1[r]); s2v = f2bf(xs2[r]); }
    const size_t o2 = (size_t)r * RS + 192;
    scA[o2] = s0v; scA[o2 + 1] = s1v; scA[o2 + 2] = s2v;
    scB[o2] = s0v; scB[o2 + 1] = s1v; scB[o2 + 2] = s2v;
  }
}

// ---------------- fused x2-gather + MFMA GEMM, XCD-pinned ------------------
// grid (8, 125), 256 thr = 4 waves. blockIdx.x = chunk == XCD. Block = 8
// nodes x 8 chunk-batches = 64 rows. Wave w owns 2 nodes (one 16-row frag).
// Phase 1 (spv-shaped, wave-uniform): wave gathers x2 = 2*(S@x1) - x0 for its
// 2 nodes (x1 = A seg1, x0 = A seg0; exact spv loop structure -> bit-identical
// values to a separate spv) and stores bf16 into an 8KB XOR-swizzled LDS tile
// (16B-chunk ^= row&7 kills the 128B-stride bank conflict, G4).
// Phase 2: MFMA ks=0..6 ascending; ks 0..3,6 A-frags from global (local L2),
// ks 4,5 from LDS. ks=7 dropped (W rows 224..255 == 0, bit-exact). W-frags
// from global (L2-hot). LDS total 8KB -> thread-capped 8 blocks/CU.
// EPI0 (NF=8, 128 cols): sig=sigmoid(y+b); col<64 -> outA seg0 = bf16(sig*h);
//                        col>=64 -> ubuf = bf16(sig)
// EPI1 (NF=4, 64 cols):  c=tanh(y+b); hn=u*h+(1-u)*c; hbuf=hn; outA seg0=bf16(hn)

template <int EPI>
__global__ __launch_bounds__(256) void k_mgf(
    const int* __restrict__ rowptr, const int* __restrict__ cols,
    const float* __restrict__ vals,
    const u16* __restrict__ A, const u16* __restrict__ Wt,
    const float* __restrict__ bias,
    u16* __restrict__ outA, u16* __restrict__ ubuf,
    float* __restrict__ hbuf) {
  constexpr int NF = EPI ? 4 : 8;
  __shared__ u16 X2[64 * 64];                  // 8 KB: 64 rows x 128B, swizzled
  const int chunk = blockIdx.x;
  const int w = threadIdx.x >> 6;
  const int l = threadIdx.x & 63;
  const int n0b = blockIdx.y * 8;

  // ---- phase 1: gather x2 for this wave's 2 nodes ----
  {
    const int bl = l >> 3, cg8 = l & 7;
    const int bphys = chunk * 8 + bl;
    const u16* in = A + 64;                    // seg1 (x1)
    const int cg = cg8 * 8;
#pragma unroll
    for (int nl2 = 0; nl2 < 2; ++nl2) {
      const int n = n0b + w * 2 + nl2;
      const int s = rowptr[n], e = rowptr[n + 1];
      float acc[8];
#pragma unroll
      for (int i = 0; i < 8; ++i) acc[i] = 0.f;
      int j = s;
      for (; j + 7 < e; j += 8) {
        float vv[8]; bf16x8 qq[8];
#pragma unroll
        for (int u8 = 0; u8 < 8; ++u8) {
          vv[u8] = vals[j + u8];
          qq[u8] = *(const bf16x8*)(in + ((size_t)cols[j + u8] * 64 + bphys) * RS + cg);
        }
#pragma unroll
        for (int i = 0; i < 8; ++i) {
          float a = acc[i];
#pragma unroll
          for (int u8 = 0; u8 < 8; ++u8) a = fmaf(vv[u8], bf2f((u16)qq[u8][i]), a);
          acc[i] = a;
        }
      }
      for (; j + 3 < e; j += 4) {
        const float v0 = vals[j],     v1 = vals[j + 1];
        const float v2 = vals[j + 2], v3 = vals[j + 3];
        bf16x8 q0 = *(const bf16x8*)(in + ((size_t)cols[j]     * 64 + bphys) * RS + cg);
        bf16x8 q1 = *(const bf16x8*)(in + ((size_t)cols[j + 1] * 64 + bphys) * RS + cg);
        bf16x8 q2 = *(const bf16x8*)(in + ((size_t)cols[j + 2] * 64 + bphys) * RS + cg);
        bf16x8 q3 = *(const bf16x8*)(in + ((size_t)cols[j + 3] * 64 + bphys) * RS + cg);
#pragma unroll
        for (int i = 0; i < 8; ++i)
          acc[i] = fmaf(v3, bf2f((u16)q3[i]),
                   fmaf(v2, bf2f((u16)q2[i]),
                   fmaf(v1, bf2f((u16)q1[i]),
                   fmaf(v0, bf2f((u16)q0[i]), acc[i]))));
      }
      for (; j < e; ++j) {
        const float v = vals[j];
        bf16x8 q = *(const bf16x8*)(in + ((size_t)cols[j] * 64 + bphys) * RS + cg);
#pragma unroll
        for (int i = 0; i < 8; ++i) acc[i] = fmaf(v, bf2f((u16)q[i]), acc[i]);
      }
      // x2 = 2*acc - x0, bf16, to swizzled LDS
      bf16x8 x0 = *(const bf16x8*)(A + ((size_t)n * 64 + bphys) * RS + cg);
      bf16x8 o;
#pragma unroll
      for (int i = 0; i < 8; ++i) o[i] = (short)f2bf(2.f * acc[i] - bf2f((u16)x0[i]));
      const int rloc = (w * 2 + nl2) * 8 + bl;
      *(bf16x8*)(X2 + rloc * 64 + ((cg8 ^ bl) * 8)) = o;
    }
  }
  __syncthreads();

  // ---- phase 2: MFMA ks 0..6 ----
  const int lr = l & 15, lk = l >> 4;
  const size_t ra = ((size_t)(n0b + w * 2 + (lr >> 3)) * 64 +
                     chunk * 8 + (lr & 7)) * RS + lk * 8;
  const u16* pw = Wt + (size_t)lr * RS + lk * 8;

  f32x4 acc[NF];
#pragma unroll
  for (int cb = 0; cb < NF; ++cb) acc[cb] = (f32x4){0.f, 0.f, 0.f, 0.f};

#pragma unroll
  for (int ks = 0; ks < 4; ++ks) {
    bf16x8 a = *(const bf16x8*)(A + ra + ks * 32);
#pragma unroll
    for (int cb = 0; cb < NF; ++cb) {
      bf16x8 bb = *(const bf16x8*)(pw + (size_t)cb * (16 * RS) + ks * 32);
      acc[cb] = __builtin_amdgcn_mfma_f32_16x16x32_bf16(a, bb, acc[cb], 0, 0, 0);
    }
  }
  const int rloc = w * 16 + lr;
#pragma unroll
  for (int k2 = 0; k2 < 2; ++k2) {
    bf16x8 a = *(const bf16x8*)(X2 + rloc * 64 + (((k2 * 4 + lk) ^ (lr & 7)) * 8));
    const int ks = 4 + k2;
#pragma unroll
    for (int cb = 0; cb < NF; ++cb) {
      bf16x8 bb = *(const bf16x8*)(pw + (size_t)cb * (16 * RS) + ks * 32);
      acc[cb] = __builtin_amdgcn_mfma_f32_16x16x32_bf16(a, bb, acc[cb], 0, 0, 0);
    }
  }
  {
    bf16x8 a = *(const bf16x8*)(A + ra + 6 * 32);
#pragma unroll
    for (int cb = 0; cb < NF; ++cb) {
      bf16x8 bb = *(const bf16x8*)(pw + (size_t)cb * (16 * RS) + 6 * 32);
      acc[cb] = __builtin_amdgcn_mfma_f32_16x16x32_bf16(a, bb, acc[cb], 0, 0, 0);
    }
  }

  // ---- epilogue ----
#pragma unroll
  for (int cb = 0; cb < NF; ++cb) {
    const int col = cb * 16 + lr;
    const float bs = bias[col];
#pragma unroll
    for (int j4 = 0; j4 < 4; ++j4) {
      const int trow = lk * 4 + j4;
      const int prow = (n0b + w * 2 + (trow >> 3)) * 64 + chunk * 8 + (trow & 7);
      const float v = acc[cb][j4] + bs;
      if (EPI == 0) {
        const float sig = 1.f / (1.f + expf(-v));
        if (col < 64)
          outA[(size_t)prow * RS + col] = f2bf(sig * hbuf[(size_t)prow * 64 + col]);
        else
          ubuf[(size_t)prow * 64 + (col - 64)] = f2bf(sig);
      } else {
        const float cc = tanhf(v);
        const size_t i64 = (size_t)prow * 64 + col;
        const float u = bf2f(ubuf[i64]);
        const float hn = u * hbuf[i64] + (1.f - u) * cc;
        hbuf[i64] = hn;
        outA[(size_t)prow * RS + col] = f2bf(hn);
      }
    }
  }
}

// ---------------- final projection ----------------

__global__ __launch_bounds__(256) void k_proj(const float* __restrict__ h,
                                              const float* __restrict__ Wp,
                                              const float* __restrict__ bp,
                                              float* __restrict__ out) {
  int lane = threadIdx.x & 63;
  int r = blockIdx.x * 4 + (threadIdx.x >> 6);
  float p = h[(size_t)r * 64 + lane] * Wp[lane];
  for (int off = 32; off; off >>= 1) p += __shfl_down(p, off, 64);
  if (lane == 0) {
    int n = r >> 6, b = r & 63;
    out[b * N + n] = p + bp[0];
  }
}

// ---------------- host launch ----------------

extern "C" void kernel_launch(void* const* d_in, const int* in_sizes, int n_in,
                              void* d_out, int out_size, void* d_ws, size_t ws_size,
                              hipStream_t stream) {
  const float* inp  = (const float*)d_in[0];
  const float* S    = (const float*)d_in[1];
  const float* eWru = (const float*)d_in[2];
  const float* ebru = (const float*)d_in[3];
  const float* eWc  = (const float*)d_in[4];
  const float* ebc  = (const float*)d_in[5];
  const float* dWru = (const float*)d_in[6];
  const float* dbru = (const float*)d_in[7];
  const float* dWc  = (const float*)d_in[8];
  const float* dbc  = (const float*)d_in[9];
  const float* Wp   = (const float*)d_in[10];
  const float* bp   = (const float*)d_in[11];
  float* out = (float*)d_out;

  char* p = (char*)d_ws;
  auto alloc = [&](size_t bytes) { void* q = p; p += (bytes + 255) & ~(size_t)255; return q; };
  u16*   A1    = (u16*)alloc((size_t)R * RS * 2);
  u16*   A2    = (u16*)alloc((size_t)R * RS * 2);
  float* hbuf  = (float*)alloc((size_t)R * 64 * 4);
  u16*   ubuf  = (u16*)alloc((size_t)R * 64 * 2);
  float* Xt    = (float*)alloc((size_t)T * R * 4);
  float* x1s   = (float*)alloc((size_t)T * R * 4);
  float* x2s   = (float*)alloc((size_t)T * R * 4);
  u16*   WtRUe = (u16*)alloc(128 * RS * 2);
  u16*   WtCe  = (u16*)alloc(64 * RS * 2);
  u16*   WtRUd = (u16*)alloc(128 * RS * 2);
  u16*   WtCd  = (u16*)alloc(64 * RS * 2);
  int*   rowptr = (int*)alloc(1024 * 4);
  int*   cols   = (int*)alloc(CSR_CAP * 4);
  float* vals   = (float*)alloc(CSR_CAP * 4);

  // initial h=0 lives in A1 seg0 (bf16) and hbuf (fp32). Scalar pad cols
  // 195..223 multiply zeroed Wt rows; cols 224..255 untouched (ks<=6);
  // seg2 (128..191) is never read (x2 lives in LDS inside k_mgf).
  k_zseg<<<2000, 256, 0, stream>>>(A1);
  hipMemsetAsync(hbuf, 0, (size_t)R * 64 * 4, stream);

  // prep: CSR, input transpose, scalar chains, transposed weights
  k_count<<<250, 256, 0, stream>>>(S, rowptr);
  k_scan<<<1, 1024, 0, stream>>>(rowptr);
  k_fill<<<250, 256, 0, stream>>>(S, rowptr, cols, vals);
  k_xt<<<dim3(16, T), 256, 0, stream>>>(inp, Xt);
  k_sspmv<<<dim3(N, T), 64, 0, stream>>>(rowptr, cols, vals, Xt, nullptr, x1s, 0);
  k_sspmv<<<dim3(N, T), 64, 0, stream>>>(rowptr, cols, vals, x1s, Xt, x2s, 1);
  k_wprep<<<dim3(128, 4), 256, 0, stream>>>(eWru, eWc, dWru, dWc,
                                            WtRUe, WtCe, WtRUd, WtCd);

  dim3 gsp(8, 250);
  dim3 gsm(8, 125);

  auto cell = [&](int t, const u16* Wru, const float* bru,
                  const u16* Wc, const float* bc) {
    const int xmode = (t >= 0) ? 1 : 2;
    const float* xs0 = (t >= 0) ? Xt  + (size_t)t * R : Xt;
    const float* xs1 = (t >= 0) ? x1s + (size_t)t * R : Xt;
    const float* xs2 = (t >= 0) ? x2s + (size_t)t * R : Xt;
    // gconv1 on A1 (seg0 = h): x1 = S@h; x2 on the fly in mgf
    k_spv<<<gsp, 256, 0, stream>>>(rowptr, cols, vals, A1,
                                   xs0, xs1, xs2, A1, A2, xmode);
    k_mgf<0><<<gsm, 256, 0, stream>>>(rowptr, cols, vals, A1, Wru, bru,
                                      A2, ubuf, hbuf);
    // gconv2 on A2 (seg0 = r.*h)
    k_spv<<<gsp, 256, 0, stream>>>(rowptr, cols, vals, A2,
                                   nullptr, nullptr, nullptr,
                                   nullptr, nullptr, 0);
    k_mgf<1><<<gsm, 256, 0, stream>>>(rowptr, cols, vals, A2, Wc, bc,
                                      A1, ubuf, hbuf);
  };

  for (int t = 0; t < T; ++t) cell(t, WtRUe, ebru, WtCe, ebc);  // encoder
  cell(-1, WtRUd, dbru, WtCd, dbc);                             // decoder

  k_proj<<<16000, 256, 0, stream>>>(hbuf, Wp, bp, out);
  (void)in_sizes; (void)n_in; (void)out_size; (void)ws_size;
}

// Round 11
// 1106.006 us; speedup vs baseline: 1.0017x; 1.0017x over previous
//
#include <hip/hip_runtime.h>
#include <hip/hip_bf16.h>

namespace {
constexpr int B  = 64;
constexpr int T  = 8;
constexpr int N  = 1000;
constexpr int U  = 64;
constexpr int R  = B * N;        // 64000 rows (r = n*64 + b)
constexpr int RS = 256;          // padded K / row stride (512B rows, line-aligned)
constexpr int CSR_CAP = 65536;
}

typedef short bf16x8 __attribute__((ext_vector_type(8)));
typedef float f32x4  __attribute__((ext_vector_type(4)));
typedef unsigned short u16;

__device__ __forceinline__ float bf2f(u16 x) {
  unsigned u = ((unsigned)x) << 16;
  float f; __builtin_memcpy(&f, &u, 4); return f;
}
__device__ __forceinline__ u16 f2bf(float f) {
  unsigned u; __builtin_memcpy(&u, &f, 4);
  u += 0x7FFFu + ((u >> 16) & 1u);
  return (u16)(u >> 16);
}

// ---------------- CSR build (deterministic, no atomics) ----------------

__global__ __launch_bounds__(256) void k_count(const float* __restrict__ S,
                                               int* __restrict__ rowptr) {
  int lane = threadIdx.x & 63;
  int m = blockIdx.x * 4 + (threadIdx.x >> 6);
  int c = 0;
  for (int n = lane; n < N; n += 64) c += (S[m * N + n] != 0.f) ? 1 : 0;
  for (int off = 32; off; off >>= 1) c += __shfl_down(c, off, 64);
  if (lane == 0) rowptr[m + 1] = c;
}

__global__ __launch_bounds__(1024) void k_scan(int* __restrict__ rowptr) {
  __shared__ int sm[1024];
  int t = threadIdx.x;
  sm[t] = (t < N) ? rowptr[t + 1] : 0;
  __syncthreads();
  for (int off = 1; off < 1024; off <<= 1) {
    int v = sm[t];
    int a = (t >= off) ? sm[t - off] : 0;
    __syncthreads();
    sm[t] = v + a;
    __syncthreads();
  }
  if (t < N) rowptr[t + 1] = sm[t];
  if (t == 0) rowptr[0] = 0;
}

__global__ __launch_bounds__(256) void k_fill(const float* __restrict__ S,
                                              const int* __restrict__ rowptr,
                                              int* __restrict__ cols,
                                              float* __restrict__ vals) {
  int lane = threadIdx.x & 63;
  int m = blockIdx.x * 4 + (threadIdx.x >> 6);
  int base = rowptr[m];
  for (int n0 = 0; n0 < N; n0 += 64) {
    int n = n0 + lane;
    float v = (n < N) ? S[m * N + n] : 0.f;
    bool nz = (v != 0.f);
    unsigned long long mask = __ballot(nz);
    int pos = base + (int)__popcll(mask & ((1ull << lane) - 1ull));
    if (nz && pos < CSR_CAP) { cols[pos] = n; vals[pos] = v; }
    base += (int)__popcll(mask);
  }
}

// ---------------- inputs transpose: (B,T,N) -> Xt[t][n*64+b] fp32 ----------

__global__ __launch_bounds__(256) void k_xt(const float* __restrict__ inp,
                                            float* __restrict__ xT) {
  __shared__ float tile[64][65];
  const int t  = blockIdx.y;
  const int n0 = blockIdx.x * 64;
  const int lx = threadIdx.x & 63;
  const int ly = threadIdx.x >> 6;
  for (int bb = ly; bb < 64; bb += 4) {
    int n = n0 + lx;
    tile[bb][lx] = (n < N) ? inp[(bb * T + t) * N + n] : 0.f;
  }
  __syncthreads();
  for (int nn = ly; nn < 64; nn += 4) {
    int n = n0 + nn;
    if (n < N) xT[((size_t)t * N + n) * 64 + lx] = tile[lx][nn];
  }
}

// ---------------- scalar Chebyshev chain (fp32, all timesteps) -------------

__global__ __launch_bounds__(64) void k_sspmv(const int* __restrict__ rowptr,
                                              const int* __restrict__ cols,
                                              const float* __restrict__ vals,
                                              const float* __restrict__ in,
                                              const float* __restrict__ sub,
                                              float* __restrict__ out, int cheb) {
  const int m = blockIdx.x, b = threadIdx.x;
  const size_t toff = (size_t)blockIdx.y * R;
  float acc = 0.f;
  for (int j = rowptr[m]; j < rowptr[m + 1]; ++j)
    acc = fmaf(vals[j], in[toff + cols[j] * 64 + b], acc);
  if (cheb) acc = 2.f * acc - sub[toff + m * 64 + b];
  out[toff + m * 64 + b] = acc;
}

// ---------------- W transpose+reorder -> Wt[o][256] bf16 -------------------
// kp<192: original row ((kp&63)+1)*3 + (kp>>6);  192..194: row kp-192; else 0.

__global__ __launch_bounds__(256) void k_wprep(
    const float* __restrict__ w0, const float* __restrict__ w1,
    const float* __restrict__ w2, const float* __restrict__ w3,
    u16* __restrict__ o0, u16* __restrict__ o1,
    u16* __restrict__ o2, u16* __restrict__ o3) {
  const float* W; u16* O; int ncol;
  switch (blockIdx.y) {
    case 0:  W = w0; O = o0; ncol = 128; break;
    case 1:  W = w1; O = o1; ncol = 64;  break;
    case 2:  W = w2; O = o2; ncol = 128; break;
    default: W = w3; O = o3; ncol = 64;  break;
  }
  int idx = blockIdx.x * 256 + threadIdx.x;
  if (idx >= ncol * RS) return;
  int o = idx / RS, kp = idx - o * RS;
  float v = 0.f;
  if (kp < 192)      v = W[(((kp & 63) + 1) * 3 + (kp >> 6)) * ncol + o];
  else if (kp < 195) v = W[(kp - 192) * ncol + o];
  O[idx] = f2bf(v);
}

// ---------------- zero seg0 of A1 (initial h = 0) --------------------------

__global__ __launch_bounds__(256) void k_zseg(u16* __restrict__ A) {
  int idx = blockIdx.x * 256 + threadIdx.x;     // 512k threads
  int r = idx >> 3, q = idx & 7;
  bf16x8 z = {0, 0, 0, 0, 0, 0, 0, 0};
  *(bf16x8*)(A + (size_t)r * RS + q * 8) = z;
}

// ---------------- bf16 diffusion spmv: seg1 = S @ seg0, XCD-pinned ---------
// grid (8, 250), 256 thr = 4 waves. blockIdx.x = chunk == XCD (x-major RR).
// Wave = ONE node m (rowptr/cols/vals wave-uniform). Lane l: batch
// b = chunk*8 + (l>>3), 8 cols at cg = (l&7)*8 (16B). j-loop unrolled x8
// (8 independent loads in flight); per-acc fmaf chain stays ascending-j.
// xmode: 1 -> write scalar cols 192..194 of scA,scB from xs*; 2 -> zeros.

__global__ __launch_bounds__(256) void k_spv(
    const int* __restrict__ rowptr, const int* __restrict__ cols,
    const float* __restrict__ vals, u16* __restrict__ A,
    const float* __restrict__ xs0, const float* __restrict__ xs1,
    const float* __restrict__ xs2,
    u16* __restrict__ scA, u16* __restrict__ scB, int xmode) {
  const int chunk = blockIdx.x;
  const int m = blockIdx.y * 4 + (threadIdx.x >> 6);
  const int l = threadIdx.x & 63;
  const int b = chunk * 8 + (l >> 3);
  const int cg = (l & 7) * 8;
  const int s = rowptr[m], e = rowptr[m + 1];

  float acc[8];
#pragma unroll
  for (int i = 0; i < 8; ++i) acc[i] = 0.f;

  const u16* in = A;                            // seg0
  int j = s;
  for (; j + 7 < e; j += 8) {
    float vv[8]; bf16x8 qq[8];
#pragma unroll
    for (int u8 = 0; u8 < 8; ++u8) {
      vv[u8] = vals[j + u8];
      qq[u8] = *(const bf16x8*)(in + ((size_t)cols[j + u8] * 64 + b) * RS + cg);
    }
#pragma unroll
    for (int i = 0; i < 8; ++i) {
      float a = acc[i];
#pragma unroll
      for (int u8 = 0; u8 < 8; ++u8) a = fmaf(vv[u8], bf2f((u16)qq[u8][i]), a);
      acc[i] = a;
    }
  }
  for (; j + 3 < e; j += 4) {
    const float v0 = vals[j],     v1 = vals[j + 1];
    const float v2 = vals[j + 2], v3 = vals[j + 3];
    bf16x8 q0 = *(const bf16x8*)(in + ((size_t)cols[j]     * 64 + b) * RS + cg);
    bf16x8 q1 = *(const bf16x8*)(in + ((size_t)cols[j + 1] * 64 + b) * RS + cg);
    bf16x8 q2 = *(const bf16x8*)(in + ((size_t)cols[j + 2] * 64 + b) * RS + cg);
    bf16x8 q3 = *(const bf16x8*)(in + ((size_t)cols[j + 3] * 64 + b) * RS + cg);
#pragma unroll
    for (int i = 0; i < 8; ++i)
      acc[i] = fmaf(v3, bf2f((u16)q3[i]),
               fmaf(v2, bf2f((u16)q2[i]),
               fmaf(v1, bf2f((u16)q1[i]),
               fmaf(v0, bf2f((u16)q0[i]), acc[i]))));
  }
  for (; j < e; ++j) {
    const float v = vals[j];
    bf16x8 q = *(const bf16x8*)(in + ((size_t)cols[j] * 64 + b) * RS + cg);
#pragma unroll
    for (int i = 0; i < 8; ++i) acc[i] = fmaf(v, bf2f((u16)q[i]), acc[i]);
  }

  const size_t ro = ((size_t)m * 64 + b) * RS + 64 + cg;   // seg1
  bf16x8 o;
#pragma unroll
  for (int i = 0; i < 8; ++i) o[i] = (short)f2bf(acc[i]);
  *(bf16x8*)(A + ro) = o;

  if (xmode && (l & 7) == 0) {
    const int r = m * 64 + b;
    u16 s0v = 0, s1v = 0, s2v = 0;
    if (xmode == 1) { s0v = f2bf(xs0[r]); s1v = f2bf(xs1[r]); s2v = f2bf(xs2[r]); }
    const size_t o2 = (size_t)r * RS + 192;
    scA[o2] = s0v; scA[o2 + 1] = s1v; scA[o2 + 2] = s2v;
    scB[o2] = s0v; scB[o2 + 1] = s1v; scB[o2 + 2] = s2v;
  }
}

// ---------------- fused x2-gather + MFMA GEMM, spv-shaped gather -----------
// grid (8, 250), 256 thr = 4 waves; 2000 blocks -> 8 blocks/CU (thread cap),
// SAME occupancy as k_spv (the r10 failure was 1000 blocks = half occupancy).
// Block = 4 nodes x 8 chunk-batches = 32 rows. blockIdx.x = chunk == XCD.
// Phase 1: wave w gathers x2 = 2*(S@x1) - x0 for node n0b+w with the EXACT
// k_spv lane layout and unroll (bit-identical values), stores bf16 into a
// 4KB XOR-swizzled LDS tile (chunk ^= batch kills the read-side conflict).
// Phase 2: 2 row-fragments (nodes {0,1},{2,3}); wave w -> frag w>>1, col-half
// w&1. ks=0..6 ascending: ks 0..3,6 A-frags from global (L2), ks 4,5 from
// LDS. ks=7 dropped (W rows 224..255 == 0, bit-exact). W from global (L2-hot,
// 57KB shared by all blocks). Cross-block phase overlap hides both latencies.
// EPI0 (128 cols, 4 cb/wave): sig=sigmoid(y+b); col<64 -> outA seg0 =
//   bf16(sig*h); col>=64 -> ubuf = bf16(sig)
// EPI1 (64 cols, 2 cb/wave): c=tanh(y+b); hn=u*h+(1-u)*c; hbuf=hn;
//   outA seg0 = bf16(hn)

template <int EPI>
__global__ __launch_bounds__(256) void k_mgf(
    const int* __restrict__ rowptr, const int* __restrict__ cols,
    const float* __restrict__ vals,
    const u16* __restrict__ A, const u16* __restrict__ Wt,
    const float* __restrict__ bias,
    u16* __restrict__ outA, u16* __restrict__ ubuf,
    float* __restrict__ hbuf) {
  constexpr int NCB = EPI ? 2 : 4;             // col-fragments per wave
  __shared__ u16 X2[32 * 64];                  // 4 KB: 32 rows x 128B, swizzled
  const int chunk = blockIdx.x;
  const int w = threadIdx.x >> 6;
  const int l = threadIdx.x & 63;
  const int n0b = blockIdx.y * 4;

  // ---- phase 1: wave w gathers x2 for node n0b + w (spv shape) ----
  {
    const int bl = l >> 3, cg8 = l & 7;
    const int bphys = chunk * 8 + bl;
    const int cg = cg8 * 8;
    const u16* in = A + 64;                    // seg1 (x1)
    const int n = n0b + w;
    const int s = rowptr[n], e = rowptr[n + 1];
    float acc[8];
#pragma unroll
    for (int i = 0; i < 8; ++i) acc[i] = 0.f;
    int j = s;
    for (; j + 7 < e; j += 8) {
      float vv[8]; bf16x8 qq[8];
#pragma unroll
      for (int u8 = 0; u8 < 8; ++u8) {
        vv[u8] = vals[j + u8];
        qq[u8] = *(const bf16x8*)(in + ((size_t)cols[j + u8] * 64 + bphys) * RS + cg);
      }
#pragma unroll
      for (int i = 0; i < 8; ++i) {
        float a = acc[i];
#pragma unroll
        for (int u8 = 0; u8 < 8; ++u8) a = fmaf(vv[u8], bf2f((u16)qq[u8][i]), a);
        acc[i] = a;
      }
    }
    for (; j + 3 < e; j += 4) {
      const float v0 = vals[j],     v1 = vals[j + 1];
      const float v2 = vals[j + 2], v3 = vals[j + 3];
      bf16x8 q0 = *(const bf16x8*)(in + ((size_t)cols[j]     * 64 + bphys) * RS + cg);
      bf16x8 q1 = *(const bf16x8*)(in + ((size_t)cols[j + 1] * 64 + bphys) * RS + cg);
      bf16x8 q2 = *(const bf16x8*)(in + ((size_t)cols[j + 2] * 64 + bphys) * RS + cg);
      bf16x8 q3 = *(const bf16x8*)(in + ((size_t)cols[j + 3] * 64 + bphys) * RS + cg);
#pragma unroll
      for (int i = 0; i < 8; ++i)
        acc[i] = fmaf(v3, bf2f((u16)q3[i]),
                 fmaf(v2, bf2f((u16)q2[i]),
                 fmaf(v1, bf2f((u16)q1[i]),
                 fmaf(v0, bf2f((u16)q0[i]), acc[i]))));
    }
    for (; j < e; ++j) {
      const float v = vals[j];
      bf16x8 q = *(const bf16x8*)(in + ((size_t)cols[j] * 64 + bphys) * RS + cg);
#pragma unroll
      for (int i = 0; i < 8; ++i) acc[i] = fmaf(v, bf2f((u16)q[i]), acc[i]);
    }
    // x2 = 2*acc - x0, bf16, to swizzled LDS
    bf16x8 x0 = *(const bf16x8*)(A + ((size_t)n * 64 + bphys) * RS + cg);
    bf16x8 o;
#pragma unroll
    for (int i = 0; i < 8; ++i) o[i] = (short)f2bf(2.f * acc[i] - bf2f((u16)x0[i]));
    *(bf16x8*)(X2 + (w * 8 + bl) * 64 + ((cg8 ^ bl) * 8)) = o;
  }
  __syncthreads();

  // ---- phase 2: MFMA ks 0..6; wave -> (row-frag, col-half) ----
  const int lr = l & 15, lk = l >> 4;
  const int f = w >> 1, ch = w & 1;
  const int colbase = ch * (EPI ? 32 : 64);
  const size_t ra = ((size_t)(n0b + 2 * f + (lr >> 3)) * 64 +
                     chunk * 8 + (lr & 7)) * RS + lk * 8;
  const u16* pw = Wt + (size_t)(colbase + lr) * RS + lk * 8;

  f32x4 acc[NCB];
#pragma unroll
  for (int cb = 0; cb < NCB; ++cb) acc[cb] = (f32x4){0.f, 0.f, 0.f, 0.f};

#pragma unroll
  for (int ks = 0; ks < 4; ++ks) {
    bf16x8 a = *(const bf16x8*)(A + ra + ks * 32);
#pragma unroll
    for (int cb = 0; cb < NCB; ++cb) {
      bf16x8 bb = *(const bf16x8*)(pw + (size_t)cb * (16 * RS) + ks * 32);
      acc[cb] = __builtin_amdgcn_mfma_f32_16x16x32_bf16(a, bb, acc[cb], 0, 0, 0);
    }
  }
  const int rloc = (2 * f + (lr >> 3)) * 8 + (lr & 7);
#pragma unroll
  for (int k2 = 0; k2 < 2; ++k2) {
    bf16x8 a = *(const bf16x8*)(X2 + rloc * 64 + (((k2 * 4 + lk) ^ (lr & 7)) * 8));
    const int ks = 4 + k2;
#pragma unroll
    for (int cb = 0; cb < NCB; ++cb) {
      bf16x8 bb = *(const bf16x8*)(pw + (size_t)cb * (16 * RS) + ks * 32);
      acc[cb] = __builtin_amdgcn_mfma_f32_16x16x32_bf16(a, bb, acc[cb], 0, 0, 0);
    }
  }
  {
    bf16x8 a = *(const bf16x8*)(A + ra + 6 * 32);
#pragma unroll
    for (int cb = 0; cb < NCB; ++cb) {
      bf16x8 bb = *(const bf16x8*)(pw + (size_t)cb * (16 * RS) + 6 * 32);
      acc[cb] = __builtin_amdgcn_mfma_f32_16x16x32_bf16(a, bb, acc[cb], 0, 0, 0);
    }
  }

  // ---- epilogue ----
#pragma unroll
  for (int cb = 0; cb < NCB; ++cb) {
    const int col = colbase + cb * 16 + lr;
    const float bs = bias[col];
#pragma unroll
    for (int j4 = 0; j4 < 4; ++j4) {
      const int trow = lk * 4 + j4;
      const int prow = (n0b + 2 * f + (trow >> 3)) * 64 + chunk * 8 + (trow & 7);
      const float v = acc[cb][j4] + bs;
      if (EPI == 0) {
        const float sig = 1.f / (1.f + expf(-v));
        if (col < 64)
          outA[(size_t)prow * RS + col] = f2bf(sig * hbuf[(size_t)prow * 64 + col]);
        else
          ubuf[(size_t)prow * 64 + (col - 64)] = f2bf(sig);
      } else {
        const float cc = tanhf(v);
        const size_t i64 = (size_t)prow * 64 + col;
        const float u = bf2f(ubuf[i64]);
        const float hn = u * hbuf[i64] + (1.f - u) * cc;
        hbuf[i64] = hn;
        outA[(size_t)prow * RS + col] = f2bf(hn);
      }
    }
  }
}

// ---------------- final projection ----------------

__global__ __launch_bounds__(256) void k_proj(const float* __restrict__ h,
                                              const float* __restrict__ Wp,
                                              const float* __restrict__ bp,
                                              float* __restrict__ out) {
  int lane = threadIdx.x & 63;
  int r = blockIdx.x * 4 + (threadIdx.x >> 6);
  float p = h[(size_t)r * 64 + lane] * Wp[lane];
  for (int off = 32; off; off >>= 1) p += __shfl_down(p, off, 64);
  if (lane == 0) {
    int n = r >> 6, b = r & 63;
    out[b * N + n] = p + bp[0];
  }
}

// ---------------- host launch ----------------

extern "C" void kernel_launch(void* const* d_in, const int* in_sizes, int n_in,
                              void* d_out, int out_size, void* d_ws, size_t ws_size,
                              hipStream_t stream) {
  const float* inp  = (const float*)d_in[0];
  const float* S    = (const float*)d_in[1];
  const float* eWru = (const float*)d_in[2];
  const float* ebru = (const float*)d_in[3];
  const float* eWc  = (const float*)d_in[4];
  const float* ebc  = (const float*)d_in[5];
  const float* dWru = (const float*)d_in[6];
  const float* dbru = (const float*)d_in[7];
  const float* dWc  = (const float*)d_in[8];
  const float* dbc  = (const float*)d_in[9];
  const float* Wp   = (const float*)d_in[10];
  const float* bp   = (const float*)d_in[11];
  float* out = (float*)d_out;

  char* p = (char*)d_ws;
  auto alloc = [&](size_t bytes) { void* q = p; p += (bytes + 255) & ~(size_t)255; return q; };
  u16*   A1    = (u16*)alloc((size_t)R * RS * 2);
  u16*   A2    = (u16*)alloc((size_t)R * RS * 2);
  float* hbuf  = (float*)alloc((size_t)R * 64 * 4);
  u16*   ubuf  = (u16*)alloc((size_t)R * 64 * 2);
  float* Xt    = (float*)alloc((size_t)T * R * 4);
  float* x1s   = (float*)alloc((size_t)T * R * 4);
  float* x2s   = (float*)alloc((size_t)T * R * 4);
  u16*   WtRUe = (u16*)alloc(128 * RS * 2);
  u16*   WtCe  = (u16*)alloc(64 * RS * 2);
  u16*   WtRUd = (u16*)alloc(128 * RS * 2);
  u16*   WtCd  = (u16*)alloc(64 * RS * 2);
  int*   rowptr = (int*)alloc(1024 * 4);
  int*   cols   = (int*)alloc(CSR_CAP * 4);
  float* vals   = (float*)alloc(CSR_CAP * 4);

  // initial h=0 lives in A1 seg0 (bf16) and hbuf (fp32). Scalar pad cols
  // 195..223 multiply zeroed Wt rows; cols 224..255 untouched (ks<=6);
  // seg2 (128..191) is never read (x2 lives in LDS inside k_mgf).
  k_zseg<<<2000, 256, 0, stream>>>(A1);
  hipMemsetAsync(hbuf, 0, (size_t)R * 64 * 4, stream);

  // prep: CSR, input transpose, scalar chains, transposed weights
  k_count<<<250, 256, 0, stream>>>(S, rowptr);
  k_scan<<<1, 1024, 0, stream>>>(rowptr);
  k_fill<<<250, 256, 0, stream>>>(S, rowptr, cols, vals);
  k_xt<<<dim3(16, T), 256, 0, stream>>>(inp, Xt);
  k_sspmv<<<dim3(N, T), 64, 0, stream>>>(rowptr, cols, vals, Xt, nullptr, x1s, 0);
  k_sspmv<<<dim3(N, T), 64, 0, stream>>>(rowptr, cols, vals, x1s, Xt, x2s, 1);
  k_wprep<<<dim3(128, 4), 256, 0, stream>>>(eWru, eWc, dWru, dWc,
                                            WtRUe, WtCe, WtRUd, WtCd);

  dim3 gsp(8, 250);

  auto cell = [&](int t, const u16* Wru, const float* bru,
                  const u16* Wc, const float* bc) {
    const int xmode = (t >= 0) ? 1 : 2;
    const float* xs0 = (t >= 0) ? Xt  + (size_t)t * R : Xt;
    const float* xs1 = (t >= 0) ? x1s + (size_t)t * R : Xt;
    const float* xs2 = (t >= 0) ? x2s + (size_t)t * R : Xt;
    // gconv1 on A1 (seg0 = h): x1 = S@h; x2 on the fly in mgf
    k_spv<<<gsp, 256, 0, stream>>>(rowptr, cols, vals, A1,
                                   xs0, xs1, xs2, A1, A2, xmode);
    k_mgf<0><<<gsp, 256, 0, stream>>>(rowptr, cols, vals, A1, Wru, bru,
                                      A2, ubuf, hbuf);
    // gconv2 on A2 (seg0 = r.*h)
    k_spv<<<gsp, 256, 0, stream>>>(rowptr, cols, vals, A2,
                                   nullptr, nullptr, nullptr,
                                   nullptr, nullptr, 0);
    k_mgf<1><<<gsp, 256, 0, stream>>>(rowptr, cols, vals, A2, Wc, bc,
                                      A1, ubuf, hbuf);
  };

  for (int t = 0; t < T; ++t) cell(t, WtRUe, ebru, WtCe, ebc);  // encoder
  cell(-1, WtRUd, dbru, WtCd, dbc);                             // decoder

  k_proj<<<16000, 256, 0, stream>>>(hbuf, Wp, bp, out);
  (void)in_sizes; (void)n_in; (void)out_size; (void)ws_size;
}

// Round 12
// 1012.693 us; speedup vs baseline: 1.0940x; 1.0921x over previous
//
#include <hip/hip_runtime.h>
#include <hip/hip_bf16.h>

namespace {
constexpr int B  = 64;
constexpr int T  = 8;
constexpr int N  = 1000;
constexpr int U  = 64;
constexpr int R  = B * N;        // 64000 rows (r = n*64 + b)
constexpr int RS = 256;          // padded K / row stride (512B rows, line-aligned)
constexpr int CSR_CAP = 65536;
}

typedef short bf16x8 __attribute__((ext_vector_type(8)));
typedef float f32x4  __attribute__((ext_vector_type(4)));
typedef unsigned short u16;

__device__ __forceinline__ float bf2f(u16 x) {
  unsigned u = ((unsigned)x) << 16;
  float f; __builtin_memcpy(&f, &u, 4); return f;
}
__device__ __forceinline__ u16 f2bf(float f) {
  unsigned u; __builtin_memcpy(&u, &f, 4);
  u += 0x7FFFu + ((u >> 16) & 1u);
  return (u16)(u >> 16);
}

// ---------------- CSR build (deterministic, no atomics) ----------------

__global__ __launch_bounds__(256) void k_count(const float* __restrict__ S,
                                               int* __restrict__ rowptr) {
  int lane = threadIdx.x & 63;
  int m = blockIdx.x * 4 + (threadIdx.x >> 6);
  int c = 0;
  for (int n = lane; n < N; n += 64) c += (S[m * N + n] != 0.f) ? 1 : 0;
  for (int off = 32; off; off >>= 1) c += __shfl_down(c, off, 64);
  if (lane == 0) rowptr[m + 1] = c;
}

__global__ __launch_bounds__(1024) void k_scan(int* __restrict__ rowptr) {
  __shared__ int sm[1024];
  int t = threadIdx.x;
  sm[t] = (t < N) ? rowptr[t + 1] : 0;
  __syncthreads();
  for (int off = 1; off < 1024; off <<= 1) {
    int v = sm[t];
    int a = (t >= off) ? sm[t - off] : 0;
    __syncthreads();
    sm[t] = v + a;
    __syncthreads();
  }
  if (t < N) rowptr[t + 1] = sm[t];
  if (t == 0) rowptr[0] = 0;
}

__global__ __launch_bounds__(256) void k_fill(const float* __restrict__ S,
                                              const int* __restrict__ rowptr,
                                              int* __restrict__ cols,
                                              float* __restrict__ vals) {
  int lane = threadIdx.x & 63;
  int m = blockIdx.x * 4 + (threadIdx.x >> 6);
  int base = rowptr[m];
  for (int n0 = 0; n0 < N; n0 += 64) {
    int n = n0 + lane;
    float v = (n < N) ? S[m * N + n] : 0.f;
    bool nz = (v != 0.f);
    unsigned long long mask = __ballot(nz);
    int pos = base + (int)__popcll(mask & ((1ull << lane) - 1ull));
    if (nz && pos < CSR_CAP) { cols[pos] = n; vals[pos] = v; }
    base += (int)__popcll(mask);
  }
}

// ---------------- inputs transpose: (B,T,N) -> Xt[t][n*64+b] fp32 ----------

__global__ __launch_bounds__(256) void k_xt(const float* __restrict__ inp,
                                            float* __restrict__ xT) {
  __shared__ float tile[64][65];
  const int t  = blockIdx.y;
  const int n0 = blockIdx.x * 64;
  const int lx = threadIdx.x & 63;
  const int ly = threadIdx.x >> 6;
  for (int bb = ly; bb < 64; bb += 4) {
    int n = n0 + lx;
    tile[bb][lx] = (n < N) ? inp[(bb * T + t) * N + n] : 0.f;
  }
  __syncthreads();
  for (int nn = ly; nn < 64; nn += 4) {
    int n = n0 + nn;
    if (n < N) xT[((size_t)t * N + n) * 64 + lx] = tile[lx][nn];
  }
}

// ---------------- scalar Chebyshev chain (fp32, all timesteps) -------------

__global__ __launch_bounds__(64) void k_sspmv(const int* __restrict__ rowptr,
                                              const int* __restrict__ cols,
                                              const float* __restrict__ vals,
                                              const float* __restrict__ in,
                                              const float* __restrict__ sub,
                                              float* __restrict__ out, int cheb) {
  const int m = blockIdx.x, b = threadIdx.x;
  const size_t toff = (size_t)blockIdx.y * R;
  float acc = 0.f;
  for (int j = rowptr[m]; j < rowptr[m + 1]; ++j)
    acc = fmaf(vals[j], in[toff + cols[j] * 64 + b], acc);
  if (cheb) acc = 2.f * acc - sub[toff + m * 64 + b];
  out[toff + m * 64 + b] = acc;
}

// ---------------- W transpose+reorder -> Wt[o][256] bf16 -------------------
// kp<192: original row ((kp&63)+1)*3 + (kp>>6);  192..194: row kp-192; else 0.

__global__ __launch_bounds__(256) void k_wprep(
    const float* __restrict__ w0, const float* __restrict__ w1,
    const float* __restrict__ w2, const float* __restrict__ w3,
    u16* __restrict__ o0, u16* __restrict__ o1,
    u16* __restrict__ o2, u16* __restrict__ o3) {
  const float* W; u16* O; int ncol;
  switch (blockIdx.y) {
    case 0:  W = w0; O = o0; ncol = 128; break;
    case 1:  W = w1; O = o1; ncol = 64;  break;
    case 2:  W = w2; O = o2; ncol = 128; break;
    default: W = w3; O = o3; ncol = 64;  break;
  }
  int idx = blockIdx.x * 256 + threadIdx.x;
  if (idx >= ncol * RS) return;
  int o = idx / RS, kp = idx - o * RS;
  float v = 0.f;
  if (kp < 192)      v = W[(((kp & 63) + 1) * 3 + (kp >> 6)) * ncol + o];
  else if (kp < 195) v = W[(kp - 192) * ncol + o];
  O[idx] = f2bf(v);
}

// ---------------- zero seg0 of A1 (initial h = 0) --------------------------

__global__ __launch_bounds__(256) void k_zseg(u16* __restrict__ A) {
  int idx = blockIdx.x * 256 + threadIdx.x;     // 512k threads
  int r = idx >> 3, q = idx & 7;
  bf16x8 z = {0, 0, 0, 0, 0, 0, 0, 0};
  *(bf16x8*)(A + (size_t)r * RS + q * 8) = z;
}

// ---------------- bf16 diffusion spmv: seg1 = S @ seg0, XCD-pinned ---------
// grid (8, 250), 256 thr = 4 waves. blockIdx.x = chunk == XCD (x-major RR).
// Wave = ONE node m (rowptr/cols/vals wave-uniform). Lane l: batch
// b = chunk*8 + (l>>3), 8 cols at cg = (l&7)*8 (16B).
// Gather loop is a DEPTH-2 software pipeline of width-4 batches: the oldest
// batch is consumed while the next 4 loads are in flight, and a refill is
// issued each iteration (max 8 loads in flight, same VGPR budget as the old
// 8-wide unroll -> occupancy unchanged). Consumption is strictly ascending-j
// with the same per-element fmaf chain -> BIT-IDENTICAL to r9.
// xmode: 1 -> write scalar cols 192..194 of scA,scB from xs*; 2 -> zeros.

__global__ __launch_bounds__(256) void k_spv(
    const int* __restrict__ rowptr, const int* __restrict__ cols,
    const float* __restrict__ vals, u16* __restrict__ A,
    const float* __restrict__ xs0, const float* __restrict__ xs1,
    const float* __restrict__ xs2,
    u16* __restrict__ scA, u16* __restrict__ scB, int xmode) {
  const int chunk = blockIdx.x;
  const int m = blockIdx.y * 4 + (threadIdx.x >> 6);
  const int l = threadIdx.x & 63;
  const int b = chunk * 8 + (l >> 3);
  const int cg = (l & 7) * 8;
  const int s = rowptr[m], e = rowptr[m + 1];
  const u16* in = A;                            // seg0
  const size_t lanoff = (size_t)b * RS + cg;

  float acc[8];
#pragma unroll
  for (int i = 0; i < 8; ++i) acc[i] = 0.f;

  bf16x8 qA[4], qB[4];
  float  vA[4], vB[4];

  auto load4 = [&](bf16x8 q[4], float v[4], int jj) {
#pragma unroll
    for (int u4 = 0; u4 < 4; ++u4) {
      v[u4] = vals[jj + u4];
      q[u4] = *(const bf16x8*)(in + (size_t)cols[jj + u4] * (64 * RS) + lanoff);
    }
  };
  auto cons4 = [&](const bf16x8 q[4], const float v[4]) {
#pragma unroll
    for (int i = 0; i < 8; ++i)
      acc[i] = fmaf(v[3], bf2f((u16)q[3][i]),
               fmaf(v[2], bf2f((u16)q[2][i]),
               fmaf(v[1], bf2f((u16)q[1][i]),
               fmaf(v[0], bf2f((u16)q[0][i]), acc[i]))));
  };

  int j = s;
  if (j + 7 < e) {
    load4(qA, vA, j);
    load4(qB, vB, j + 4);
    j += 8;
    int useA = 1;
    for (; j + 3 < e; j += 4) {
      if (useA) { cons4(qA, vA); load4(qA, vA, j); }
      else      { cons4(qB, vB); load4(qB, vB, j); }
      useA ^= 1;
    }
    if (useA) { cons4(qA, vA); cons4(qB, vB); }   // ascending drain
    else      { cons4(qB, vB); cons4(qA, vA); }
  }
  for (; j < e; ++j) {
    const float v = vals[j];
    bf16x8 q = *(const bf16x8*)(in + (size_t)cols[j] * (64 * RS) + lanoff);
#pragma unroll
    for (int i = 0; i < 8; ++i) acc[i] = fmaf(v, bf2f((u16)q[i]), acc[i]);
  }

  const size_t ro = ((size_t)m * 64 + b) * RS + 64 + cg;   // seg1
  bf16x8 o;
#pragma unroll
  for (int i = 0; i < 8; ++i) o[i] = (short)f2bf(acc[i]);
  *(bf16x8*)(A + ro) = o;

  if (xmode && (l & 7) == 0) {
    const int r = m * 64 + b;
    u16 s0v = 0, s1v = 0, s2v = 0;
    if (xmode == 1) { s0v = f2bf(xs0[r]); s1v = f2bf(xs1[r]); s2v = f2bf(xs2[r]); }
    const size_t o2 = (size_t)r * RS + 192;
    scA[o2] = s0v; scA[o2 + 1] = s1v; scA[o2 + 2] = s2v;
    scB[o2] = s0v; scB[o2 + 1] = s1v; scB[o2 + 2] = s2v;
  }
}

// ---------------- bf16 diffusion spmv: seg2 = 2*(S @ seg1) - seg0 ----------
// Same shape/pipeline as k_spv; reads seg1, applies Chebyshev recurrence
// against seg0, writes seg2. Bit-identical math to r9's sub-variant.

__global__ __launch_bounds__(256) void k_spv2(
    const int* __restrict__ rowptr, const int* __restrict__ cols,
    const float* __restrict__ vals, u16* __restrict__ A) {
  const int chunk = blockIdx.x;
  const int m = blockIdx.y * 4 + (threadIdx.x >> 6);
  const int l = threadIdx.x & 63;
  const int b = chunk * 8 + (l >> 3);
  const int cg = (l & 7) * 8;
  const int s = rowptr[m], e = rowptr[m + 1];
  const u16* in = A + 64;                       // seg1
  const size_t lanoff = (size_t)b * RS + cg;

  float acc[8];
#pragma unroll
  for (int i = 0; i < 8; ++i) acc[i] = 0.f;

  bf16x8 qA[4], qB[4];
  float  vA[4], vB[4];

  auto load4 = [&](bf16x8 q[4], float v[4], int jj) {
#pragma unroll
    for (int u4 = 0; u4 < 4; ++u4) {
      v[u4] = vals[jj + u4];
      q[u4] = *(const bf16x8*)(in + (size_t)cols[jj + u4] * (64 * RS) + lanoff);
    }
  };
  auto cons4 = [&](const bf16x8 q[4], const float v[4]) {
#pragma unroll
    for (int i = 0; i < 8; ++i)
      acc[i] = fmaf(v[3], bf2f((u16)q[3][i]),
               fmaf(v[2], bf2f((u16)q[2][i]),
               fmaf(v[1], bf2f((u16)q[1][i]),
               fmaf(v[0], bf2f((u16)q[0][i]), acc[i]))));
  };

  int j = s;
  if (j + 7 < e) {
    load4(qA, vA, j);
    load4(qB, vB, j + 4);
    j += 8;
    int useA = 1;
    for (; j + 3 < e; j += 4) {
      if (useA) { cons4(qA, vA); load4(qA, vA, j); }
      else      { cons4(qB, vB); load4(qB, vB, j); }
      useA ^= 1;
    }
    if (useA) { cons4(qA, vA); cons4(qB, vB); }
    else      { cons4(qB, vB); cons4(qA, vA); }
  }
  for (; j < e; ++j) {
    const float v = vals[j];
    bf16x8 q = *(const bf16x8*)(in + (size_t)cols[j] * (64 * RS) + lanoff);
#pragma unroll
    for (int i = 0; i < 8; ++i) acc[i] = fmaf(v, bf2f((u16)q[i]), acc[i]);
  }

  const size_t rb = ((size_t)m * 64 + b) * RS + cg;
  bf16x8 sb = *(const bf16x8*)(A + rb);         // seg0 (sub)
  bf16x8 o;
#pragma unroll
  for (int i = 0; i < 8; ++i) o[i] = (short)f2bf(2.f * acc[i] - bf2f((u16)sb[i]));
  *(bf16x8*)(A + rb + 128) = o;                 // seg2
}

// ---------------- MFMA GEMM, XCD-pinned, K-halved LDS staging --------------
// (identical to r9 — proven 12 µs) 128 thr = 2 waves; ks 0..6 (ks=7 dropped:
// W rows 224..255 == 0, bit-exact). W staged per K-half into 16KB LDS,
// XOR-swizzled (chunk ^= row&7). EPI0: grid (8,125,2); EPI1: grid (8,250).

template <int EPI>
__global__ __launch_bounds__(128) void k_mg2(
    const u16* __restrict__ A, const u16* __restrict__ Wt,
    const float* __restrict__ bias,
    u16* __restrict__ outA, u16* __restrict__ ubuf,
    float* __restrict__ hbuf) {
  __shared__ u16 Wl[64 * 128];                 // 16 KB, one K-half
  const int chunk = blockIdx.x;
  const int ob = EPI ? 0 : blockIdx.z * 64;
  const int wv = threadIdx.x >> 6;
  const int n0 = EPI ? (blockIdx.y * 4 + wv * 2) : (blockIdx.y * 8 + wv * 4);
  const int l  = threadIdx.x & 63;
  const int lr = l & 15, lk = l >> 4;
  const int bphys = chunk * 8 + (lr & 7);
  const int tc = threadIdx.x & 15, tr0 = threadIdx.x >> 4;   // staging decomp

  const size_t ra0 = ((size_t)(n0 + (lr >> 3)) * 64 + bphys) * RS + lk * 8;
  const size_t ra1 = ra0 + 2 * 64 * RS;        // nodes n0+2, n0+3 (EPI0 only)

  f32x4 acc[2][4];
#pragma unroll
  for (int i = 0; i < 2; ++i)
#pragma unroll
    for (int j = 0; j < 4; ++j) acc[i][j] = (f32x4){0.f, 0.f, 0.f, 0.f};

  // ---- K-half 0: k 0..127 (16 chunks/row) ----
  for (int r = tr0; r < 64; r += 8)
    *(bf16x8*)(Wl + r * 128 + ((tc ^ (r & 7)) * 8)) =
        *(const bf16x8*)(Wt + (size_t)(ob + r) * RS + tc * 8);
  __syncthreads();
#pragma unroll
  for (int ks = 0; ks < 4; ++ks) {
    bf16x8 a0 = *(const bf16x8*)(A + ra0 + ks * 32);
    bf16x8 a1;
    if (!EPI) a1 = *(const bf16x8*)(A + ra1 + ks * 32);
#pragma unroll
    for (int cb = 0; cb < 4; ++cb) {
      const int wrow = cb * 16 + lr;
      bf16x8 bb = *(const bf16x8*)(Wl + wrow * 128 +
                                   (((ks * 4 + lk) ^ (wrow & 7)) * 8));
      acc[0][cb] = __builtin_amdgcn_mfma_f32_16x16x32_bf16(a0, bb, acc[0][cb], 0, 0, 0);
      if (!EPI)
        acc[1][cb] = __builtin_amdgcn_mfma_f32_16x16x32_bf16(a1, bb, acc[1][cb], 0, 0, 0);
    }
  }
  __syncthreads();
  // ---- K-half 1: k 128..223 (12 chunks/row) ----
  if (tc < 12)
    for (int r = tr0; r < 64; r += 8)
      *(bf16x8*)(Wl + r * 128 + ((tc ^ (r & 7)) * 8)) =
          *(const bf16x8*)(Wt + (size_t)(ob + r) * RS + 128 + tc * 8);
  __syncthreads();
#pragma unroll
  for (int ks = 4; ks < 7; ++ks) {
    bf16x8 a0 = *(const bf16x8*)(A + ra0 + ks * 32);
    bf16x8 a1;
    if (!EPI) a1 = *(const bf16x8*)(A + ra1 + ks * 32);
#pragma unroll
    for (int cb = 0; cb < 4; ++cb) {
      const int wrow = cb * 16 + lr;
      bf16x8 bb = *(const bf16x8*)(Wl + wrow * 128 +
                                   ((((ks - 4) * 4 + lk) ^ (wrow & 7)) * 8));
      acc[0][cb] = __builtin_amdgcn_mfma_f32_16x16x32_bf16(a0, bb, acc[0][cb], 0, 0, 0);
      if (!EPI)
        acc[1][cb] = __builtin_amdgcn_mfma_f32_16x16x32_bf16(a1, bb, acc[1][cb], 0, 0, 0);
    }
  }

  // ---- epilogue ----
#pragma unroll
  for (int mf = 0; mf < (EPI ? 1 : 2); ++mf)
#pragma unroll
    for (int cb = 0; cb < 4; ++cb) {
      const int col = ob + cb * 16 + lr;
      const float bs = bias[col];
#pragma unroll
      for (int j4 = 0; j4 < 4; ++j4) {
        const int trow = lk * 4 + j4;
        const int prow = (n0 + mf * 2 + (trow >> 3)) * 64 + chunk * 8 + (trow & 7);
        const float v = acc[mf][cb][j4] + bs;
        if (EPI == 0) {
          const float sig = 1.f / (1.f + expf(-v));
          if (col < 64)
            outA[(size_t)prow * RS + col] = f2bf(sig * hbuf[(size_t)prow * 64 + col]);
          else
            ubuf[(size_t)prow * 64 + (col - 64)] = f2bf(sig);
        } else {
          const float cc = tanhf(v);
          const size_t i64 = (size_t)prow * 64 + col;
          const float u = bf2f(ubuf[i64]);
          const float hn = u * hbuf[i64] + (1.f - u) * cc;
          hbuf[i64] = hn;
          outA[(size_t)prow * RS + col] = f2bf(hn);
        }
      }
    }
}

// ---------------- final projection ----------------

__global__ __launch_bounds__(256) void k_proj(const float* __restrict__ h,
                                              const float* __restrict__ Wp,
                                              const float* __restrict__ bp,
                                              float* __restrict__ out) {
  int lane = threadIdx.x & 63;
  int r = blockIdx.x * 4 + (threadIdx.x >> 6);
  float p = h[(size_t)r * 64 + lane] * Wp[lane];
  for (int off = 32; off; off >>= 1) p += __shfl_down(p, off, 64);
  if (lane == 0) {
    int n = r >> 6, b = r & 63;
    out[b * N + n] = p + bp[0];
  }
}

// ---------------- host launch ----------------

extern "C" void kernel_launch(void* const* d_in, const int* in_sizes, int n_in,
                              void* d_out, int out_size, void* d_ws, size_t ws_size,
                              hipStream_t stream) {
  const float* inp  = (const float*)d_in[0];
  const float* S    = (const float*)d_in[1];
  const float* eWru = (const float*)d_in[2];
  const float* ebru = (const float*)d_in[3];
  const float* eWc  = (const float*)d_in[4];
  const float* ebc  = (const float*)d_in[5];
  const float* dWru = (const float*)d_in[6];
  const float* dbru = (const float*)d_in[7];
  const float* dWc  = (const float*)d_in[8];
  const float* dbc  = (const float*)d_in[9];
  const float* Wp   = (const float*)d_in[10];
  const float* bp   = (const float*)d_in[11];
  float* out = (float*)d_out;

  char* p = (char*)d_ws;
  auto alloc = [&](size_t bytes) { void* q = p; p += (bytes + 255) & ~(size_t)255; return q; };
  u16*   A1    = (u16*)alloc((size_t)R * RS * 2);
  u16*   A2    = (u16*)alloc((size_t)R * RS * 2);
  float* hbuf  = (float*)alloc((size_t)R * 64 * 4);
  u16*   ubuf  = (u16*)alloc((size_t)R * 64 * 2);
  float* Xt    = (float*)alloc((size_t)T * R * 4);
  float* x1s   = (float*)alloc((size_t)T * R * 4);
  float* x2s   = (float*)alloc((size_t)T * R * 4);
  u16*   WtRUe = (u16*)alloc(128 * RS * 2);
  u16*   WtCe  = (u16*)alloc(64 * RS * 2);
  u16*   WtRUd = (u16*)alloc(128 * RS * 2);
  u16*   WtCd  = (u16*)alloc(64 * RS * 2);
  int*   rowptr = (int*)alloc(1024 * 4);
  int*   cols   = (int*)alloc(CSR_CAP * 4);
  float* vals   = (float*)alloc(CSR_CAP * 4);

  // initial h=0 lives in A1 seg0 (bf16) and hbuf (fp32). Scalar pad cols
  // 195..223 multiply zeroed Wt rows; cols 224..255 untouched (ks<=6).
  k_zseg<<<2000, 256, 0, stream>>>(A1);
  hipMemsetAsync(hbuf, 0, (size_t)R * 64 * 4, stream);

  // prep: CSR, input transpose, scalar chains, transposed weights
  k_count<<<250, 256, 0, stream>>>(S, rowptr);
  k_scan<<<1, 1024, 0, stream>>>(rowptr);
  k_fill<<<250, 256, 0, stream>>>(S, rowptr, cols, vals);
  k_xt<<<dim3(16, T), 256, 0, stream>>>(inp, Xt);
  k_sspmv<<<dim3(N, T), 64, 0, stream>>>(rowptr, cols, vals, Xt, nullptr, x1s, 0);
  k_sspmv<<<dim3(N, T), 64, 0, stream>>>(rowptr, cols, vals, x1s, Xt, x2s, 1);
  k_wprep<<<dim3(128, 4), 256, 0, stream>>>(eWru, eWc, dWru, dWc,
                                            WtRUe, WtCe, WtRUd, WtCd);

  dim3 gsp(8, 250);

  auto cell = [&](int t, const u16* Wru, const float* bru,
                  const u16* Wc, const float* bc) {
    const int xmode = (t >= 0) ? 1 : 2;
    const float* xs0 = (t >= 0) ? Xt  + (size_t)t * R : Xt;
    const float* xs1 = (t >= 0) ? x1s + (size_t)t * R : Xt;
    const float* xs2 = (t >= 0) ? x2s + (size_t)t * R : Xt;
    // gconv1 on A1 (seg0 = h): x1 = S@h, x2 = 2*S@x1 - h
    k_spv<<<gsp, 256, 0, stream>>>(rowptr, cols, vals, A1,
                                   xs0, xs1, xs2, A1, A2, xmode);
    k_spv2<<<gsp, 256, 0, stream>>>(rowptr, cols, vals, A1);
    k_mg2<0><<<dim3(8, 125, 2), 128, 0, stream>>>(A1, Wru, bru, A2, ubuf, hbuf);
    // gconv2 on A2 (seg0 = r.*h)
    k_spv<<<gsp, 256, 0, stream>>>(rowptr, cols, vals, A2,
                                   nullptr, nullptr, nullptr,
                                   nullptr, nullptr, 0);
    k_spv2<<<gsp, 256, 0, stream>>>(rowptr, cols, vals, A2);
    k_mg2<1><<<dim3(8, 250), 128, 0, stream>>>(A2, Wc, bc, A1, ubuf, hbuf);
  };

  for (int t = 0; t < T; ++t) cell(t, WtRUe, ebru, WtCe, ebc);  // encoder
  cell(-1, WtRUd, dbru, WtCd, dbc);                             // decoder

  k_proj<<<16000, 256, 0, stream>>>(hbuf, Wp, bp, out);
  (void)in_sizes; (void)n_in; (void)out_size; (void)ws_size;
}

// Round 13
// 894.711 us; speedup vs baseline: 1.2383x; 1.1319x over previous
//
#include <hip/hip_runtime.h>
#include <hip/hip_bf16.h>

namespace {
constexpr int B  = 64;
constexpr int T  = 8;
constexpr int N  = 1000;
constexpr int U  = 64;
constexpr int R  = B * N;        // 64000 rows (r = n*64 + b)
constexpr int RS = 256;          // padded K / row stride (512B rows, line-aligned)
constexpr int CSR_CAP = 65536;
}

typedef short bf16x8 __attribute__((ext_vector_type(8)));
typedef float f32x4  __attribute__((ext_vector_type(4)));
typedef unsigned short u16;

__device__ __forceinline__ float bf2f(u16 x) {
  unsigned u = ((unsigned)x) << 16;
  float f; __builtin_memcpy(&f, &u, 4); return f;
}
__device__ __forceinline__ u16 f2bf(float f) {
  unsigned u; __builtin_memcpy(&u, &f, 4);
  u += 0x7FFFu + ((u >> 16) & 1u);
  return (u16)(u >> 16);
}

// ---------------- CSR build (deterministic, no atomics) ----------------

__global__ __launch_bounds__(256) void k_count(const float* __restrict__ S,
                                               int* __restrict__ rowptr) {
  int lane = threadIdx.x & 63;
  int m = blockIdx.x * 4 + (threadIdx.x >> 6);
  int c = 0;
  for (int n = lane; n < N; n += 64) c += (S[m * N + n] != 0.f) ? 1 : 0;
  for (int off = 32; off; off >>= 1) c += __shfl_down(c, off, 64);
  if (lane == 0) rowptr[m + 1] = c;
}

__global__ __launch_bounds__(1024) void k_scan(int* __restrict__ rowptr) {
  __shared__ int sm[1024];
  int t = threadIdx.x;
  sm[t] = (t < N) ? rowptr[t + 1] : 0;
  __syncthreads();
  for (int off = 1; off < 1024; off <<= 1) {
    int v = sm[t];
    int a = (t >= off) ? sm[t - off] : 0;
    __syncthreads();
    sm[t] = v + a;
    __syncthreads();
  }
  if (t < N) rowptr[t + 1] = sm[t];
  if (t == 0) rowptr[0] = 0;
}

__global__ __launch_bounds__(256) void k_fill(const float* __restrict__ S,
                                              const int* __restrict__ rowptr,
                                              int* __restrict__ cols,
                                              float* __restrict__ vals) {
  int lane = threadIdx.x & 63;
  int m = blockIdx.x * 4 + (threadIdx.x >> 6);
  int base = rowptr[m];
  for (int n0 = 0; n0 < N; n0 += 64) {
    int n = n0 + lane;
    float v = (n < N) ? S[m * N + n] : 0.f;
    bool nz = (v != 0.f);
    unsigned long long mask = __ballot(nz);
    int pos = base + (int)__popcll(mask & ((1ull << lane) - 1ull));
    if (nz && pos < CSR_CAP) { cols[pos] = n; vals[pos] = v; }
    base += (int)__popcll(mask);
  }
}

// ---------------- inputs transpose: (B,T,N) -> Xt[t][n*64+b] fp32 ----------

__global__ __launch_bounds__(256) void k_xt(const float* __restrict__ inp,
                                            float* __restrict__ xT) {
  __shared__ float tile[64][65];
  const int t  = blockIdx.y;
  const int n0 = blockIdx.x * 64;
  const int lx = threadIdx.x & 63;
  const int ly = threadIdx.x >> 6;
  for (int bb = ly; bb < 64; bb += 4) {
    int n = n0 + lx;
    tile[bb][lx] = (n < N) ? inp[(bb * T + t) * N + n] : 0.f;
  }
  __syncthreads();
  for (int nn = ly; nn < 64; nn += 4) {
    int n = n0 + nn;
    if (n < N) xT[((size_t)t * N + n) * 64 + lx] = tile[lx][nn];
  }
}

// ---------------- scalar Chebyshev chain (fp32, all timesteps) -------------
// 256-thr blocks (4 nodes each); same per-element ascending-j fmaf chain.

__global__ __launch_bounds__(256) void k_sspmv(const int* __restrict__ rowptr,
                                               const int* __restrict__ cols,
                                               const float* __restrict__ vals,
                                               const float* __restrict__ in,
                                               const float* __restrict__ sub,
                                               float* __restrict__ out, int cheb) {
  const int m = blockIdx.x * 4 + (threadIdx.x >> 6);
  const int b = threadIdx.x & 63;
  const size_t toff = (size_t)blockIdx.y * R;
  float acc = 0.f;
  for (int j = rowptr[m]; j < rowptr[m + 1]; ++j)
    acc = fmaf(vals[j], in[toff + cols[j] * 64 + b], acc);
  if (cheb) acc = 2.f * acc - sub[toff + m * 64 + b];
  out[toff + m * 64 + b] = acc;
}

// ---------------- W transpose+reorder -> Wt[o][256] bf16 -------------------
// kp<192: original row ((kp&63)+1)*3 + (kp>>6);  192..194: row kp-192; else 0.

__global__ __launch_bounds__(256) void k_wprep(
    const float* __restrict__ w0, const float* __restrict__ w1,
    const float* __restrict__ w2, const float* __restrict__ w3,
    u16* __restrict__ o0, u16* __restrict__ o1,
    u16* __restrict__ o2, u16* __restrict__ o3) {
  const float* W; u16* O; int ncol;
  switch (blockIdx.y) {
    case 0:  W = w0; O = o0; ncol = 128; break;
    case 1:  W = w1; O = o1; ncol = 64;  break;
    case 2:  W = w2; O = o2; ncol = 128; break;
    default: W = w3; O = o3; ncol = 64;  break;
  }
  int idx = blockIdx.x * 256 + threadIdx.x;
  if (idx >= ncol * RS) return;
  int o = idx / RS, kp = idx - o * RS;
  float v = 0.f;
  if (kp < 192)      v = W[(((kp & 63) + 1) * 3 + (kp >> 6)) * ncol + o];
  else if (kp < 195) v = W[(kp - 192) * ncol + o];
  O[idx] = f2bf(v);
}

// ---------------- zero seg0 of A1 (initial h = 0) --------------------------

__global__ __launch_bounds__(256) void k_zseg(u16* __restrict__ A) {
  int idx = blockIdx.x * 256 + threadIdx.x;     // 512k threads
  int r = idx >> 3, q = idx & 7;
  bf16x8 z = {0, 0, 0, 0, 0, 0, 0, 0};
  *(bf16x8*)(A + (size_t)r * RS + q * 8) = z;
}

// ---------------- bf16 diffusion spmv: seg1 = S @ seg0, XCD-pinned ---------
// (r9's proven loop: plain 8-wide unroll; compiler schedules the 8 loads.)
// grid (8, 250), 256 thr = 4 waves. blockIdx.x = chunk == XCD (x-major RR).
// Wave = ONE node m (rowptr/cols/vals wave-uniform). Lane l: batch
// b = chunk*8 + (l>>3), 8 cols at cg = (l&7)*8 (16B).
// xmode: 1 -> write scalar cols 192..194 of scA,scB from xs*; 2 -> zeros.

__global__ __launch_bounds__(256) void k_spv(
    const int* __restrict__ rowptr, const int* __restrict__ cols,
    const float* __restrict__ vals, u16* __restrict__ A,
    const float* __restrict__ xs0, const float* __restrict__ xs1,
    const float* __restrict__ xs2,
    u16* __restrict__ scA, u16* __restrict__ scB, int xmode) {
  const int chunk = blockIdx.x;
  const int m = blockIdx.y * 4 + (threadIdx.x >> 6);
  const int l = threadIdx.x & 63;
  const int b = chunk * 8 + (l >> 3);
  const int cg = (l & 7) * 8;
  const int s = rowptr[m], e = rowptr[m + 1];
  const u16* in = A;                            // seg0

  float acc[8];
#pragma unroll
  for (int i = 0; i < 8; ++i) acc[i] = 0.f;

  int j = s;
  for (; j + 7 < e; j += 8) {
    float vv[8]; bf16x8 qq[8];
#pragma unroll
    for (int u8 = 0; u8 < 8; ++u8) {
      vv[u8] = vals[j + u8];
      qq[u8] = *(const bf16x8*)(in + ((size_t)cols[j + u8] * 64 + b) * RS + cg);
    }
#pragma unroll
    for (int i = 0; i < 8; ++i) {
      float a = acc[i];
#pragma unroll
      for (int u8 = 0; u8 < 8; ++u8) a = fmaf(vv[u8], bf2f((u16)qq[u8][i]), a);
      acc[i] = a;
    }
  }
  for (; j + 3 < e; j += 4) {
    const float v0 = vals[j],     v1 = vals[j + 1];
    const float v2 = vals[j + 2], v3 = vals[j + 3];
    bf16x8 q0 = *(const bf16x8*)(in + ((size_t)cols[j]     * 64 + b) * RS + cg);
    bf16x8 q1 = *(const bf16x8*)(in + ((size_t)cols[j + 1] * 64 + b) * RS + cg);
    bf16x8 q2 = *(const bf16x8*)(in + ((size_t)cols[j + 2] * 64 + b) * RS + cg);
    bf16x8 q3 = *(const bf16x8*)(in + ((size_t)cols[j + 3] * 64 + b) * RS + cg);
#pragma unroll
    for (int i = 0; i < 8; ++i)
      acc[i] = fmaf(v3, bf2f((u16)q3[i]),
               fmaf(v2, bf2f((u16)q2[i]),
               fmaf(v1, bf2f((u16)q1[i]),
               fmaf(v0, bf2f((u16)q0[i]), acc[i]))));
  }
  for (; j < e; ++j) {
    const float v = vals[j];
    bf16x8 q = *(const bf16x8*)(in + ((size_t)cols[j] * 64 + b) * RS + cg);
#pragma unroll
    for (int i = 0; i < 8; ++i) acc[i] = fmaf(v, bf2f((u16)q[i]), acc[i]);
  }

  const size_t ro = ((size_t)m * 64 + b) * RS + 64 + cg;   // seg1
  bf16x8 o;
#pragma unroll
  for (int i = 0; i < 8; ++i) o[i] = (short)f2bf(acc[i]);
  *(bf16x8*)(A + ro) = o;

  if (xmode && (l & 7) == 0) {
    const int r = m * 64 + b;
    u16 s0v = 0, s1v = 0, s2v = 0;
    if (xmode == 1) { s0v = f2bf(xs0[r]); s1v = f2bf(xs1[r]); s2v = f2bf(xs2[r]); }
    const size_t o2 = (size_t)r * RS + 192;
    scA[o2] = s0v; scA[o2 + 1] = s1v; scA[o2 + 2] = s2v;
    scB[o2] = s0v; scB[o2 + 1] = s1v; scB[o2 + 2] = s2v;
  }
}

// ---------------- bf16 diffusion spmv: seg2 = 2*(S @ seg1) - seg0 ----------
// Same r9-style 8-wide unroll; reads seg1, Chebyshev vs seg0, writes seg2.

__global__ __launch_bounds__(256) void k_spv2(
    const int* __restrict__ rowptr, const int* __restrict__ cols,
    const float* __restrict__ vals, u16* __restrict__ A) {
  const int chunk = blockIdx.x;
  const int m = blockIdx.y * 4 + (threadIdx.x >> 6);
  const int l = threadIdx.x & 63;
  const int b = chunk * 8 + (l >> 3);
  const int cg = (l & 7) * 8;
  const int s = rowptr[m], e = rowptr[m + 1];
  const u16* in = A + 64;                       // seg1

  float acc[8];
#pragma unroll
  for (int i = 0; i < 8; ++i) acc[i] = 0.f;

  int j = s;
  for (; j + 7 < e; j += 8) {
    float vv[8]; bf16x8 qq[8];
#pragma unroll
    for (int u8 = 0; u8 < 8; ++u8) {
      vv[u8] = vals[j + u8];
      qq[u8] = *(const bf16x8*)(in + ((size_t)cols[j + u8] * 64 + b) * RS + cg);
    }
#pragma unroll
    for (int i = 0; i < 8; ++i) {
      float a = acc[i];
#pragma unroll
      for (int u8 = 0; u8 < 8; ++u8) a = fmaf(vv[u8], bf2f((u16)qq[u8][i]), a);
      acc[i] = a;
    }
  }
  for (; j + 3 < e; j += 4) {
    const float v0 = vals[j],     v1 = vals[j + 1];
    const float v2 = vals[j + 2], v3 = vals[j + 3];
    bf16x8 q0 = *(const bf16x8*)(in + ((size_t)cols[j]     * 64 + b) * RS + cg);
    bf16x8 q1 = *(const bf16x8*)(in + ((size_t)cols[j + 1] * 64 + b) * RS + cg);
    bf16x8 q2 = *(const bf16x8*)(in + ((size_t)cols[j + 2] * 64 + b) * RS + cg);
    bf16x8 q3 = *(const bf16x8*)(in + ((size_t)cols[j + 3] * 64 + b) * RS + cg);
#pragma unroll
    for (int i = 0; i < 8; ++i)
      acc[i] = fmaf(v3, bf2f((u16)q3[i]),
               fmaf(v2, bf2f((u16)q2[i]),
               fmaf(v1, bf2f((u16)q1[i]),
               fmaf(v0, bf2f((u16)q0[i]), acc[i]))));
  }
  for (; j < e; ++j) {
    const float v = vals[j];
    bf16x8 q = *(const bf16x8*)(in + ((size_t)cols[j] * 64 + b) * RS + cg);
#pragma unroll
    for (int i = 0; i < 8; ++i) acc[i] = fmaf(v, bf2f((u16)q[i]), acc[i]);
  }

  const size_t rb = ((size_t)m * 64 + b) * RS + cg;
  bf16x8 sb = *(const bf16x8*)(A + rb);         // seg0 (sub)
  bf16x8 o;
#pragma unroll
  for (int i = 0; i < 8; ++i) o[i] = (short)f2bf(2.f * acc[i] - bf2f((u16)sb[i]));
  *(bf16x8*)(A + rb + 128) = o;                 // seg2
}

// ---------------- MFMA GEMM, XCD-pinned, K-halved LDS, 256-thr -------------
// 256 thr = 4 waves, 16KB LDS -> thread-capped 8 blocks/CU = 100% occupancy
// (r9's 128-thr was LDS-capped at 62%). Wave = ONE 16-row frag (2 nodes x 8
// chunk-batches) x 64 cols (4 cb). Block = 8 nodes. ks 0..6 ascending, same
// cb split as r9 -> per-output accumulation order identical (bit-exact).
// ks=7 dropped (W rows 224..255 == 0). W staged per K-half into 16KB LDS,
// XOR-swizzled (chunk ^= row&7) on write and read (G4).
// EPI0: grid (8,125,2), z = col-half (ob). EPI1: grid (8,125), ob=0.
// Epilogues unchanged from r9.

template <int EPI>
__global__ __launch_bounds__(256) void k_mg2(
    const u16* __restrict__ A, const u16* __restrict__ Wt,
    const float* __restrict__ bias,
    u16* __restrict__ outA, u16* __restrict__ ubuf,
    float* __restrict__ hbuf) {
  __shared__ u16 Wl[64 * 128];                 // 16 KB, one K-half
  const int chunk = blockIdx.x;
  const int ob = EPI ? 0 : blockIdx.z * 64;
  const int w  = threadIdx.x >> 6;
  const int n0 = blockIdx.y * 8;
  const int l  = threadIdx.x & 63;
  const int lr = l & 15, lk = l >> 4;
  const int bphys = chunk * 8 + (lr & 7);
  const int tc = threadIdx.x & 15, tr0 = threadIdx.x >> 4;   // 16 rows x 16 chunks

  const int nA = n0 + 2 * w + (lr >> 3);
  const size_t ra = ((size_t)nA * 64 + bphys) * RS + lk * 8;

  f32x4 acc[4];
#pragma unroll
  for (int cb = 0; cb < 4; ++cb) acc[cb] = (f32x4){0.f, 0.f, 0.f, 0.f};

  // ---- K-half 0: k 0..127 (16 chunks/row) ----
  for (int r = tr0; r < 64; r += 16)
    *(bf16x8*)(Wl + r * 128 + ((tc ^ (r & 7)) * 8)) =
        *(const bf16x8*)(Wt + (size_t)(ob + r) * RS + tc * 8);
  __syncthreads();
#pragma unroll
  for (int ks = 0; ks < 4; ++ks) {
    bf16x8 a = *(const bf16x8*)(A + ra + ks * 32);
#pragma unroll
    for (int cb = 0; cb < 4; ++cb) {
      const int wrow = cb * 16 + lr;
      bf16x8 bb = *(const bf16x8*)(Wl + wrow * 128 +
                                   (((ks * 4 + lk) ^ (wrow & 7)) * 8));
      acc[cb] = __builtin_amdgcn_mfma_f32_16x16x32_bf16(a, bb, acc[cb], 0, 0, 0);
    }
  }
  __syncthreads();
  // ---- K-half 1: k 128..223 (12 chunks/row) ----
  if (tc < 12)
    for (int r = tr0; r < 64; r += 16)
      *(bf16x8*)(Wl + r * 128 + ((tc ^ (r & 7)) * 8)) =
          *(const bf16x8*)(Wt + (size_t)(ob + r) * RS + 128 + tc * 8);
  __syncthreads();
#pragma unroll
  for (int ks = 4; ks < 7; ++ks) {
    bf16x8 a = *(const bf16x8*)(A + ra + ks * 32);
#pragma unroll
    for (int cb = 0; cb < 4; ++cb) {
      const int wrow = cb * 16 + lr;
      bf16x8 bb = *(const bf16x8*)(Wl + wrow * 128 +
                                   ((((ks - 4) * 4 + lk) ^ (wrow & 7)) * 8));
      acc[cb] = __builtin_amdgcn_mfma_f32_16x16x32_bf16(a, bb, acc[cb], 0, 0, 0);
    }
  }

  // ---- epilogue ----
#pragma unroll
  for (int cb = 0; cb < 4; ++cb) {
    const int col = ob + cb * 16 + lr;
    const float bs = bias[col];
#pragma unroll
    for (int j4 = 0; j4 < 4; ++j4) {
      const int trow = lk * 4 + j4;
      const int prow = (n0 + 2 * w + (trow >> 3)) * 64 + chunk * 8 + (trow & 7);
      const float v = acc[cb][j4] + bs;
      if (EPI == 0) {
        const float sig = 1.f / (1.f + expf(-v));
        if (col < 64)
          outA[(size_t)prow * RS + col] = f2bf(sig * hbuf[(size_t)prow * 64 + col]);
        else
          ubuf[(size_t)prow * 64 + (col - 64)] = f2bf(sig);
      } else {
        const float cc = tanhf(v);
        const size_t i64 = (size_t)prow * 64 + col;
        const float u = bf2f(ubuf[i64]);
        const float hn = u * hbuf[i64] + (1.f - u) * cc;
        hbuf[i64] = hn;
        outA[(size_t)prow * RS + col] = f2bf(hn);
      }
    }
  }
}

// ---------------- final projection ----------------

__global__ __launch_bounds__(256) void k_proj(const float* __restrict__ h,
                                              const float* __restrict__ Wp,
                                              const float* __restrict__ bp,
                                              float* __restrict__ out) {
  int lane = threadIdx.x & 63;
  int r = blockIdx.x * 4 + (threadIdx.x >> 6);
  float p = h[(size_t)r * 64 + lane] * Wp[lane];
  for (int off = 32; off; off >>= 1) p += __shfl_down(p, off, 64);
  if (lane == 0) {
    int n = r >> 6, b = r & 63;
    out[b * N + n] = p + bp[0];
  }
}

// ---------------- host launch ----------------

extern "C" void kernel_launch(void* const* d_in, const int* in_sizes, int n_in,
                              void* d_out, int out_size, void* d_ws, size_t ws_size,
                              hipStream_t stream) {
  const float* inp  = (const float*)d_in[0];
  const float* S    = (const float*)d_in[1];
  const float* eWru = (const float*)d_in[2];
  const float* ebru = (const float*)d_in[3];
  const float* eWc  = (const float*)d_in[4];
  const float* ebc  = (const float*)d_in[5];
  const float* dWru = (const float*)d_in[6];
  const float* dbru = (const float*)d_in[7];
  const float* dWc  = (const float*)d_in[8];
  const float* dbc  = (const float*)d_in[9];
  const float* Wp   = (const float*)d_in[10];
  const float* bp   = (const float*)d_in[11];
  float* out = (float*)d_out;

  char* p = (char*)d_ws;
  auto alloc = [&](size_t bytes) { void* q = p; p += (bytes + 255) & ~(size_t)255; return q; };
  u16*   A1    = (u16*)alloc((size_t)R * RS * 2);
  u16*   A2    = (u16*)alloc((size_t)R * RS * 2);
  float* hbuf  = (float*)alloc((size_t)R * 64 * 4);
  u16*   ubuf  = (u16*)alloc((size_t)R * 64 * 2);
  float* Xt    = (float*)alloc((size_t)T * R * 4);
  float* x1s   = (float*)alloc((size_t)T * R * 4);
  float* x2s   = (float*)alloc((size_t)T * R * 4);
  u16*   WtRUe = (u16*)alloc(128 * RS * 2);
  u16*   WtCe  = (u16*)alloc(64 * RS * 2);
  u16*   WtRUd = (u16*)alloc(128 * RS * 2);
  u16*   WtCd  = (u16*)alloc(64 * RS * 2);
  int*   rowptr = (int*)alloc(1024 * 4);
  int*   cols   = (int*)alloc(CSR_CAP * 4);
  float* vals   = (float*)alloc(CSR_CAP * 4);

  // initial h=0 lives in A1 seg0 (bf16) and hbuf (fp32). Scalar pad cols
  // 195..223 multiply zeroed Wt rows; cols 224..255 untouched (ks<=6).
  k_zseg<<<2000, 256, 0, stream>>>(A1);
  hipMemsetAsync(hbuf, 0, (size_t)R * 64 * 4, stream);

  // prep: CSR, input transpose, scalar chains, transposed weights
  k_count<<<250, 256, 0, stream>>>(S, rowptr);
  k_scan<<<1, 1024, 0, stream>>>(rowptr);
  k_fill<<<250, 256, 0, stream>>>(S, rowptr, cols, vals);
  k_xt<<<dim3(16, T), 256, 0, stream>>>(inp, Xt);
  k_sspmv<<<dim3(250, T), 256, 0, stream>>>(rowptr, cols, vals, Xt, nullptr, x1s, 0);
  k_sspmv<<<dim3(250, T), 256, 0, stream>>>(rowptr, cols, vals, x1s, Xt, x2s, 1);
  k_wprep<<<dim3(128, 4), 256, 0, stream>>>(eWru, eWc, dWru, dWc,
                                            WtRUe, WtCe, WtRUd, WtCd);

  dim3 gsp(8, 250);

  auto cell = [&](int t, const u16* Wru, const float* bru,
                  const u16* Wc, const float* bc) {
    const int xmode = (t >= 0) ? 1 : 2;
    const float* xs0 = (t >= 0) ? Xt  + (size_t)t * R : Xt;
    const float* xs1 = (t >= 0) ? x1s + (size_t)t * R : Xt;
    const float* xs2 = (t >= 0) ? x2s + (size_t)t * R : Xt;
    // gconv1 on A1 (seg0 = h): x1 = S@h, x2 = 2*S@x1 - h
    k_spv<<<gsp, 256, 0, stream>>>(rowptr, cols, vals, A1,
                                   xs0, xs1, xs2, A1, A2, xmode);
    k_spv2<<<gsp, 256, 0, stream>>>(rowptr, cols, vals, A1);
    k_mg2<0><<<dim3(8, 125, 2), 256, 0, stream>>>(A1, Wru, bru, A2, ubuf, hbuf);
    // gconv2 on A2 (seg0 = r.*h)
    k_spv<<<gsp, 256, 0, stream>>>(rowptr, cols, vals, A2,
                                   nullptr, nullptr, nullptr,
                                   nullptr, nullptr, 0);
    k_spv2<<<gsp, 256, 0, stream>>>(rowptr, cols, vals, A2);
    k_mg2<1><<<dim3(8, 125), 256, 0, stream>>>(A2, Wc, bc, A1, ubuf, hbuf);
  };

  for (int t = 0; t < T; ++t) cell(t, WtRUe, ebru, WtCe, ebc);  // encoder
  cell(-1, WtRUd, dbru, WtCd, dbc);                             // decoder

  k_proj<<<16000, 256, 0, stream>>>(hbuf, Wp, bp, out);
  (void)in_sizes; (void)n_in; (void)out_size; (void)ws_size;
}

// Round 14
// 792.708 us; speedup vs baseline: 1.3976x; 1.1287x over previous
//
#include <hip/hip_runtime.h>
#include <hip/hip_bf16.h>

namespace {
constexpr int B  = 64;
constexpr int T  = 8;
constexpr int N  = 1000;
constexpr int U  = 64;
constexpr int R  = B * N;        // 64000 rows (r = n*64 + b)
constexpr int RS = 256;          // padded K / row stride (512B rows, line-aligned)
constexpr int CSR_CAP = 65536;
}

typedef short bf16x8 __attribute__((ext_vector_type(8)));
typedef float f32x4  __attribute__((ext_vector_type(4)));
typedef unsigned short u16;

__device__ __forceinline__ float bf2f(u16 x) {
  unsigned u = ((unsigned)x) << 16;
  float f; __builtin_memcpy(&f, &u, 4); return f;
}
__device__ __forceinline__ u16 f2bf(float f) {
  unsigned u; __builtin_memcpy(&u, &f, 4);
  u += 0x7FFFu + ((u >> 16) & 1u);
  return (u16)(u >> 16);
}

// ---------------- CSR build (deterministic, no atomics) ----------------

__global__ __launch_bounds__(256) void k_count(const float* __restrict__ S,
                                               int* __restrict__ rowptr) {
  int lane = threadIdx.x & 63;
  int m = blockIdx.x * 4 + (threadIdx.x >> 6);
  int c = 0;
  for (int n = lane; n < N; n += 64) c += (S[m * N + n] != 0.f) ? 1 : 0;
  for (int off = 32; off; off >>= 1) c += __shfl_down(c, off, 64);
  if (lane == 0) rowptr[m + 1] = c;
}

__global__ __launch_bounds__(1024) void k_scan(int* __restrict__ rowptr) {
  __shared__ int sm[1024];
  int t = threadIdx.x;
  sm[t] = (t < N) ? rowptr[t + 1] : 0;
  __syncthreads();
  for (int off = 1; off < 1024; off <<= 1) {
    int v = sm[t];
    int a = (t >= off) ? sm[t - off] : 0;
    __syncthreads();
    sm[t] = v + a;
    __syncthreads();
  }
  if (t < N) rowptr[t + 1] = sm[t];
  if (t == 0) rowptr[0] = 0;
}

__global__ __launch_bounds__(256) void k_fill(const float* __restrict__ S,
                                              const int* __restrict__ rowptr,
                                              int* __restrict__ cols,
                                              float* __restrict__ vals) {
  int lane = threadIdx.x & 63;
  int m = blockIdx.x * 4 + (threadIdx.x >> 6);
  int base = rowptr[m];
  for (int n0 = 0; n0 < N; n0 += 64) {
    int n = n0 + lane;
    float v = (n < N) ? S[m * N + n] : 0.f;
    bool nz = (v != 0.f);
    unsigned long long mask = __ballot(nz);
    int pos = base + (int)__popcll(mask & ((1ull << lane) - 1ull));
    if (nz && pos < CSR_CAP) { cols[pos] = n; vals[pos] = v; }
    base += (int)__popcll(mask);
  }
}

// ---------------- inputs transpose: (B,T,N) -> Xt[t][n*64+b] fp32 ----------

__global__ __launch_bounds__(256) void k_xt(const float* __restrict__ inp,
                                            float* __restrict__ xT) {
  __shared__ float tile[64][65];
  const int t  = blockIdx.y;
  const int n0 = blockIdx.x * 64;
  const int lx = threadIdx.x & 63;
  const int ly = threadIdx.x >> 6;
  for (int bb = ly; bb < 64; bb += 4) {
    int n = n0 + lx;
    tile[bb][lx] = (n < N) ? inp[(bb * T + t) * N + n] : 0.f;
  }
  __syncthreads();
  for (int nn = ly; nn < 64; nn += 4) {
    int n = n0 + nn;
    if (n < N) xT[((size_t)t * N + n) * 64 + lx] = tile[lx][nn];
  }
}

// ---------------- scalar Chebyshev chain (fp32, all timesteps) -------------
// 256-thr blocks (4 nodes each). m made wave-uniform via readfirstlane so
// rowptr/cols/vals go down the scalar (s_load) path.

__global__ __launch_bounds__(256) void k_sspmv(const int* __restrict__ rowptr,
                                               const int* __restrict__ cols,
                                               const float* __restrict__ vals,
                                               const float* __restrict__ in,
                                               const float* __restrict__ sub,
                                               float* __restrict__ out, int cheb) {
  const int wv = __builtin_amdgcn_readfirstlane(threadIdx.x >> 6);
  const int m = blockIdx.x * 4 + wv;
  const int b = threadIdx.x & 63;
  const size_t toff = (size_t)blockIdx.y * R;
  float acc = 0.f;
  const int s = rowptr[m], e = rowptr[m + 1];
  for (int j = s; j < e; ++j)
    acc = fmaf(vals[j], in[toff + cols[j] * 64 + b], acc);
  if (cheb) acc = 2.f * acc - sub[toff + m * 64 + b];
  out[toff + m * 64 + b] = acc;
}

// ---------------- W transpose+reorder -> Wt[o][256] bf16 -------------------
// kp<192: original row ((kp&63)+1)*3 + (kp>>6);  192..194: row kp-192; else 0.

__global__ __launch_bounds__(256) void k_wprep(
    const float* __restrict__ w0, const float* __restrict__ w1,
    const float* __restrict__ w2, const float* __restrict__ w3,
    u16* __restrict__ o0, u16* __restrict__ o1,
    u16* __restrict__ o2, u16* __restrict__ o3) {
  const float* W; u16* O; int ncol;
  switch (blockIdx.y) {
    case 0:  W = w0; O = o0; ncol = 128; break;
    case 1:  W = w1; O = o1; ncol = 64;  break;
    case 2:  W = w2; O = o2; ncol = 128; break;
    default: W = w3; O = o3; ncol = 64;  break;
  }
  int idx = blockIdx.x * 256 + threadIdx.x;
  if (idx >= ncol * RS) return;
  int o = idx / RS, kp = idx - o * RS;
  float v = 0.f;
  if (kp < 192)      v = W[(((kp & 63) + 1) * 3 + (kp >> 6)) * ncol + o];
  else if (kp < 195) v = W[(kp - 192) * ncol + o];
  O[idx] = f2bf(v);
}

// ---------------- zero seg0 of A1 (initial h = 0) --------------------------

__global__ __launch_bounds__(256) void k_zseg(u16* __restrict__ A) {
  int idx = blockIdx.x * 256 + threadIdx.x;     // 512k threads
  int r = idx >> 3, q = idx & 7;
  bf16x8 z = {0, 0, 0, 0, 0, 0, 0, 0};
  *(bf16x8*)(A + (size_t)r * RS + q * 8) = z;
}

// ---------------- bf16 diffusion spmv: seg1 = S @ seg0, XCD-pinned ---------
// grid (8, 250), 256 thr = 4 waves. blockIdx.x = chunk == XCD (x-major RR).
// Wave = ONE node m, made wave-uniform via readfirstlane: rowptr/cols/vals
// become SGPR s_loads (1 vector VMEM per nnz instead of 3; data-load address
// is SGPR-base + VGPR-lane-offset). Lane l: batch b = chunk*8 + (l>>3),
// 8 cols at cg = (l&7)*8. 8-wide unroll (r9-proven). Values identical ->
// bit-exact. xmode: 1 -> write scalar cols 192..194 from xs*; 2 -> zeros.

__global__ __launch_bounds__(256) void k_spv(
    const int* __restrict__ rowptr, const int* __restrict__ cols,
    const float* __restrict__ vals, u16* __restrict__ A,
    const float* __restrict__ xs0, const float* __restrict__ xs1,
    const float* __restrict__ xs2,
    u16* __restrict__ scA, u16* __restrict__ scB, int xmode) {
  const int chunk = blockIdx.x;
  const int wv = __builtin_amdgcn_readfirstlane(threadIdx.x >> 6);
  const int m = blockIdx.y * 4 + wv;
  const int l = threadIdx.x & 63;
  const int b = chunk * 8 + (l >> 3);
  const int cg = (l & 7) * 8;
  const int s = rowptr[m], e = rowptr[m + 1];
  const u16* in = A;                            // seg0

  float acc[8];
#pragma unroll
  for (int i = 0; i < 8; ++i) acc[i] = 0.f;

  int j = s;
  for (; j + 7 < e; j += 8) {
    float vv[8]; bf16x8 qq[8];
#pragma unroll
    for (int u8 = 0; u8 < 8; ++u8) {
      vv[u8] = vals[j + u8];
      qq[u8] = *(const bf16x8*)(in + ((size_t)cols[j + u8] * 64 + b) * RS + cg);
    }
#pragma unroll
    for (int i = 0; i < 8; ++i) {
      float a = acc[i];
#pragma unroll
      for (int u8 = 0; u8 < 8; ++u8) a = fmaf(vv[u8], bf2f((u16)qq[u8][i]), a);
      acc[i] = a;
    }
  }
  for (; j + 3 < e; j += 4) {
    const float v0 = vals[j],     v1 = vals[j + 1];
    const float v2 = vals[j + 2], v3 = vals[j + 3];
    bf16x8 q0 = *(const bf16x8*)(in + ((size_t)cols[j]     * 64 + b) * RS + cg);
    bf16x8 q1 = *(const bf16x8*)(in + ((size_t)cols[j + 1] * 64 + b) * RS + cg);
    bf16x8 q2 = *(const bf16x8*)(in + ((size_t)cols[j + 2] * 64 + b) * RS + cg);
    bf16x8 q3 = *(const bf16x8*)(in + ((size_t)cols[j + 3] * 64 + b) * RS + cg);
#pragma unroll
    for (int i = 0; i < 8; ++i)
      acc[i] = fmaf(v3, bf2f((u16)q3[i]),
               fmaf(v2, bf2f((u16)q2[i]),
               fmaf(v1, bf2f((u16)q1[i]),
               fmaf(v0, bf2f((u16)q0[i]), acc[i]))));
  }
  for (; j < e; ++j) {
    const float v = vals[j];
    bf16x8 q = *(const bf16x8*)(in + ((size_t)cols[j] * 64 + b) * RS + cg);
#pragma unroll
    for (int i = 0; i < 8; ++i) acc[i] = fmaf(v, bf2f((u16)q[i]), acc[i]);
  }

  const size_t ro = ((size_t)m * 64 + b) * RS + 64 + cg;   // seg1
  bf16x8 o;
#pragma unroll
  for (int i = 0; i < 8; ++i) o[i] = (short)f2bf(acc[i]);
  *(bf16x8*)(A + ro) = o;

  if (xmode && (l & 7) == 0) {
    const int r = m * 64 + b;
    u16 s0v = 0, s1v = 0, s2v = 0;
    if (xmode == 1) { s0v = f2bf(xs0[r]); s1v = f2bf(xs1[r]); s2v = f2bf(xs2[r]); }
    const size_t o2 = (size_t)r * RS + 192;
    scA[o2] = s0v; scA[o2 + 1] = s1v; scA[o2 + 2] = s2v;
    scB[o2] = s0v; scB[o2 + 1] = s1v; scB[o2 + 2] = s2v;
  }
}

// ---------------- bf16 diffusion spmv: seg2 = 2*(S @ seg1) - seg0 ----------
// Same scalarized shape; reads seg1, Chebyshev vs seg0, writes seg2.

__global__ __launch_bounds__(256) void k_spv2(
    const int* __restrict__ rowptr, const int* __restrict__ cols,
    const float* __restrict__ vals, u16* __restrict__ A) {
  const int chunk = blockIdx.x;
  const int wv = __builtin_amdgcn_readfirstlane(threadIdx.x >> 6);
  const int m = blockIdx.y * 4 + wv;
  const int l = threadIdx.x & 63;
  const int b = chunk * 8 + (l >> 3);
  const int cg = (l & 7) * 8;
  const int s = rowptr[m], e = rowptr[m + 1];
  const u16* in = A + 64;                       // seg1

  float acc[8];
#pragma unroll
  for (int i = 0; i < 8; ++i) acc[i] = 0.f;

  int j = s;
  for (; j + 7 < e; j += 8) {
    float vv[8]; bf16x8 qq[8];
#pragma unroll
    for (int u8 = 0; u8 < 8; ++u8) {
      vv[u8] = vals[j + u8];
      qq[u8] = *(const bf16x8*)(in + ((size_t)cols[j + u8] * 64 + b) * RS + cg);
    }
#pragma unroll
    for (int i = 0; i < 8; ++i) {
      float a = acc[i];
#pragma unroll
      for (int u8 = 0; u8 < 8; ++u8) a = fmaf(vv[u8], bf2f((u16)qq[u8][i]), a);
      acc[i] = a;
    }
  }
  for (; j + 3 < e; j += 4) {
    const float v0 = vals[j],     v1 = vals[j + 1];
    const float v2 = vals[j + 2], v3 = vals[j + 3];
    bf16x8 q0 = *(const bf16x8*)(in + ((size_t)cols[j]     * 64 + b) * RS + cg);
    bf16x8 q1 = *(const bf16x8*)(in + ((size_t)cols[j + 1] * 64 + b) * RS + cg);
    bf16x8 q2 = *(const bf16x8*)(in + ((size_t)cols[j + 2] * 64 + b) * RS + cg);
    bf16x8 q3 = *(const bf16x8*)(in + ((size_t)cols[j + 3] * 64 + b) * RS + cg);
#pragma unroll
    for (int i = 0; i < 8; ++i)
      acc[i] = fmaf(v3, bf2f((u16)q3[i]),
               fmaf(v2, bf2f((u16)q2[i]),
               fmaf(v1, bf2f((u16)q1[i]),
               fmaf(v0, bf2f((u16)q0[i]), acc[i]))));
  }
  for (; j < e; ++j) {
    const float v = vals[j];
    bf16x8 q = *(const bf16x8*)(in + ((size_t)cols[j] * 64 + b) * RS + cg);
#pragma unroll
    for (int i = 0; i < 8; ++i) acc[i] = fmaf(v, bf2f((u16)q[i]), acc[i]);
  }

  const size_t rb = ((size_t)m * 64 + b) * RS + cg;
  bf16x8 sb = *(const bf16x8*)(A + rb);         // seg0 (sub)
  bf16x8 o;
#pragma unroll
  for (int i = 0; i < 8; ++i) o[i] = (short)f2bf(2.f * acc[i] - bf2f((u16)sb[i]));
  *(bf16x8*)(A + rb + 128) = o;                 // seg2
}

// ---------------- MFMA GEMM, XCD-pinned, K-halved LDS, 256-thr -------------
// (r13-proven: 100% occupancy, bit-exact.) ks 0..6 ascending; ks=7 dropped.
// W staged per K-half into 16KB LDS, XOR-swizzled (chunk ^= row&7).
// EPI0: grid (8,125,2), z = col-half (ob). EPI1: grid (8,125), ob=0.

template <int EPI>
__global__ __launch_bounds__(256) void k_mg2(
    const u16* __restrict__ A, const u16* __restrict__ Wt,
    const float* __restrict__ bias,
    u16* __restrict__ outA, u16* __restrict__ ubuf,
    float* __restrict__ hbuf) {
  __shared__ u16 Wl[64 * 128];                 // 16 KB, one K-half
  const int chunk = blockIdx.x;
  const int ob = EPI ? 0 : blockIdx.z * 64;
  const int w  = threadIdx.x >> 6;
  const int n0 = blockIdx.y * 8;
  const int l  = threadIdx.x & 63;
  const int lr = l & 15, lk = l >> 4;
  const int bphys = chunk * 8 + (lr & 7);
  const int tc = threadIdx.x & 15, tr0 = threadIdx.x >> 4;   // 16 rows x 16 chunks

  const int nA = n0 + 2 * w + (lr >> 3);
  const size_t ra = ((size_t)nA * 64 + bphys) * RS + lk * 8;

  f32x4 acc[4];
#pragma unroll
  for (int cb = 0; cb < 4; ++cb) acc[cb] = (f32x4){0.f, 0.f, 0.f, 0.f};

  // ---- K-half 0: k 0..127 (16 chunks/row) ----
  for (int r = tr0; r < 64; r += 16)
    *(bf16x8*)(Wl + r * 128 + ((tc ^ (r & 7)) * 8)) =
        *(const bf16x8*)(Wt + (size_t)(ob + r) * RS + tc * 8);
  __syncthreads();
#pragma unroll
  for (int ks = 0; ks < 4; ++ks) {
    bf16x8 a = *(const bf16x8*)(A + ra + ks * 32);
#pragma unroll
    for (int cb = 0; cb < 4; ++cb) {
      const int wrow = cb * 16 + lr;
      bf16x8 bb = *(const bf16x8*)(Wl + wrow * 128 +
                                   (((ks * 4 + lk) ^ (wrow & 7)) * 8));
      acc[cb] = __builtin_amdgcn_mfma_f32_16x16x32_bf16(a, bb, acc[cb], 0, 0, 0);
    }
  }
  __syncthreads();
  // ---- K-half 1: k 128..223 (12 chunks/row) ----
  if (tc < 12)
    for (int r = tr0; r < 64; r += 16)
      *(bf16x8*)(Wl + r * 128 + ((tc ^ (r & 7)) * 8)) =
          *(const bf16x8*)(Wt + (size_t)(ob + r) * RS + 128 + tc * 8);
  __syncthreads();
#pragma unroll
  for (int ks = 4; ks < 7; ++ks) {
    bf16x8 a = *(const bf16x8*)(A + ra + ks * 32);
#pragma unroll
    for (int cb = 0; cb < 4; ++cb) {
      const int wrow = cb * 16 + lr;
      bf16x8 bb = *(const bf16x8*)(Wl + wrow * 128 +
                                   ((((ks - 4) * 4 + lk) ^ (wrow & 7)) * 8));
      acc[cb] = __builtin_amdgcn_mfma_f32_16x16x32_bf16(a, bb, acc[cb], 0, 0, 0);
    }
  }

  // ---- epilogue ----
#pragma unroll
  for (int cb = 0; cb < 4; ++cb) {
    const int col = ob + cb * 16 + lr;
    const float bs = bias[col];
#pragma unroll
    for (int j4 = 0; j4 < 4; ++j4) {
      const int trow = lk * 4 + j4;
      const int prow = (n0 + 2 * w + (trow >> 3)) * 64 + chunk * 8 + (trow & 7);
      const float v = acc[cb][j4] + bs;
      if (EPI == 0) {
        const float sig = 1.f / (1.f + expf(-v));
        if (col < 64)
          outA[(size_t)prow * RS + col] = f2bf(sig * hbuf[(size_t)prow * 64 + col]);
        else
          ubuf[(size_t)prow * 64 + (col - 64)] = f2bf(sig);
      } else {
        const float cc = tanhf(v);
        const size_t i64 = (size_t)prow * 64 + col;
        const float u = bf2f(ubuf[i64]);
        const float hn = u * hbuf[i64] + (1.f - u) * cc;
        hbuf[i64] = hn;
        outA[(size_t)prow * RS + col] = f2bf(hn);
      }
    }
  }
}

// ---------------- final projection ----------------

__global__ __launch_bounds__(256) void k_proj(const float* __restrict__ h,
                                              const float* __restrict__ Wp,
                                              const float* __restrict__ bp,
                                              float* __restrict__ out) {
  int lane = threadIdx.x & 63;
  int r = blockIdx.x * 4 + (threadIdx.x >> 6);
  float p = h[(size_t)r * 64 + lane] * Wp[lane];
  for (int off = 32; off; off >>= 1) p += __shfl_down(p, off, 64);
  if (lane == 0) {
    int n = r >> 6, b = r & 63;
    out[b * N + n] = p + bp[0];
  }
}

// ---------------- host launch ----------------

extern "C" void kernel_launch(void* const* d_in, const int* in_sizes, int n_in,
                              void* d_out, int out_size, void* d_ws, size_t ws_size,
                              hipStream_t stream) {
  const float* inp  = (const float*)d_in[0];
  const float* S    = (const float*)d_in[1];
  const float* eWru = (const float*)d_in[2];
  const float* ebru = (const float*)d_in[3];
  const float* eWc  = (const float*)d_in[4];
  const float* ebc  = (const float*)d_in[5];
  const float* dWru = (const float*)d_in[6];
  const float* dbru = (const float*)d_in[7];
  const float* dWc  = (const float*)d_in[8];
  const float* dbc  = (const float*)d_in[9];
  const float* Wp   = (const float*)d_in[10];
  const float* bp   = (const float*)d_in[11];
  float* out = (float*)d_out;

  char* p = (char*)d_ws;
  auto alloc = [&](size_t bytes) { void* q = p; p += (bytes + 255) & ~(size_t)255; return q; };
  u16*   A1    = (u16*)alloc((size_t)R * RS * 2);
  u16*   A2    = (u16*)alloc((size_t)R * RS * 2);
  float* hbuf  = (float*)alloc((size_t)R * 64 * 4);
  u16*   ubuf  = (u16*)alloc((size_t)R * 64 * 2);
  float* Xt    = (float*)alloc((size_t)T * R * 4);
  float* x1s   = (float*)alloc((size_t)T * R * 4);
  float* x2s   = (float*)alloc((size_t)T * R * 4);
  u16*   WtRUe = (u16*)alloc(128 * RS * 2);
  u16*   WtCe  = (u16*)alloc(64 * RS * 2);
  u16*   WtRUd = (u16*)alloc(128 * RS * 2);
  u16*   WtCd  = (u16*)alloc(64 * RS * 2);
  int*   rowptr = (int*)alloc(1024 * 4);
  int*   cols   = (int*)alloc(CSR_CAP * 4);
  float* vals   = (float*)alloc(CSR_CAP * 4);

  // initial h=0 lives in A1 seg0 (bf16) and hbuf (fp32). Scalar pad cols
  // 195..223 multiply zeroed Wt rows; cols 224..255 untouched (ks<=6).
  k_zseg<<<2000, 256, 0, stream>>>(A1);
  hipMemsetAsync(hbuf, 0, (size_t)R * 64 * 4, stream);

  // prep: CSR, input transpose, scalar chains, transposed weights
  k_count<<<250, 256, 0, stream>>>(S, rowptr);
  k_scan<<<1, 1024, 0, stream>>>(rowptr);
  k_fill<<<250, 256, 0, stream>>>(S, rowptr, cols, vals);
  k_xt<<<dim3(16, T), 256, 0, stream>>>(inp, Xt);
  k_sspmv<<<dim3(250, T), 256, 0, stream>>>(rowptr, cols, vals, Xt, nullptr, x1s, 0);
  k_sspmv<<<dim3(250, T), 256, 0, stream>>>(rowptr, cols, vals, x1s, Xt, x2s, 1);
  k_wprep<<<dim3(128, 4), 256, 0, stream>>>(eWru, eWc, dWru, dWc,
                                            WtRUe, WtCe, WtRUd, WtCd);

  dim3 gsp(8, 250);

  auto cell = [&](int t, const u16* Wru, const float* bru,
                  const u16* Wc, const float* bc) {
    const int xmode = (t >= 0) ? 1 : 2;
    const float* xs0 = (t >= 0) ? Xt  + (size_t)t * R : Xt;
    const float* xs1 = (t >= 0) ? x1s + (size_t)t * R : Xt;
    const float* xs2 = (t >= 0) ? x2s + (size_t)t * R : Xt;
    // gconv1 on A1 (seg0 = h): x1 = S@h, x2 = 2*S@x1 - h
    k_spv<<<gsp, 256, 0, stream>>>(rowptr, cols, vals, A1,
                                   xs0, xs1, xs2, A1, A2, xmode);
    k_spv2<<<gsp, 256, 0, stream>>>(rowptr, cols, vals, A1);
    k_mg2<0><<<dim3(8, 125, 2), 256, 0, stream>>>(A1, Wru, bru, A2, ubuf, hbuf);
    // gconv2 on A2 (seg0 = r.*h)
    k_spv<<<gsp, 256, 0, stream>>>(rowptr, cols, vals, A2,
                                   nullptr, nullptr, nullptr,
                                   nullptr, nullptr, 0);
    k_spv2<<<gsp, 256, 0, stream>>>(rowptr, cols, vals, A2);
    k_mg2<1><<<dim3(8, 125), 256, 0, stream>>>(A2, Wc, bc, A1, ubuf, hbuf);
  };

  for (int t = 0; t < T; ++t) cell(t, WtRUe, ebru, WtCe, ebc);  // encoder
  cell(-1, WtRUd, dbru, WtCd, dbc);                             // decoder

  k_proj<<<16000, 256, 0, stream>>>(hbuf, Wp, bp, out);
  (void)in_sizes; (void)n_in; (void)out_size; (void)ws_size;
}

// Round 16
// 790.164 us; speedup vs baseline: 1.4021x; 1.0032x over previous
//
#include <hip/hip_runtime.h>
#include <hip/hip_bf16.h>

namespace {
constexpr int B  = 64;
constexpr int T  = 8;
constexpr int N  = 1000;
constexpr int U  = 64;
constexpr int R  = B * N;        // 64000 rows (r = n*64 + b)
constexpr int RS = 256;          // padded K / row stride (512B rows, line-aligned)
constexpr int CSR_CAP = 65536;
}

typedef short bf16x8 __attribute__((ext_vector_type(8)));
typedef float f32x4  __attribute__((ext_vector_type(4)));
typedef unsigned short u16;

__device__ __forceinline__ float bf2f(u16 x) {
  unsigned u = ((unsigned)x) << 16;
  float f; __builtin_memcpy(&f, &u, 4); return f;
}
__device__ __forceinline__ u16 f2bf(float f) {
  unsigned u; __builtin_memcpy(&u, &f, 4);
  u += 0x7FFFu + ((u >> 16) & 1u);
  return (u16)(u >> 16);
}

// ---------------- CSR build (deterministic, no atomics) ----------------

__global__ __launch_bounds__(256) void k_count(const float* __restrict__ S,
                                               int* __restrict__ rowptr) {
  int lane = threadIdx.x & 63;
  int m = blockIdx.x * 4 + (threadIdx.x >> 6);
  int c = 0;
  for (int n = lane; n < N; n += 64) c += (S[m * N + n] != 0.f) ? 1 : 0;
  for (int off = 32; off; off >>= 1) c += __shfl_down(c, off, 64);
  if (lane == 0) rowptr[m + 1] = c;
}

__global__ __launch_bounds__(1024) void k_scan(int* __restrict__ rowptr) {
  __shared__ int sm[1024];
  int t = threadIdx.x;
  sm[t] = (t < N) ? rowptr[t + 1] : 0;
  __syncthreads();
  for (int off = 1; off < 1024; off <<= 1) {
    int v = sm[t];
    int a = (t >= off) ? sm[t - off] : 0;
    __syncthreads();
    sm[t] = v + a;
    __syncthreads();
  }
  if (t < N) rowptr[t + 1] = sm[t];
  if (t == 0) rowptr[0] = 0;
}

__global__ __launch_bounds__(256) void k_fill(const float* __restrict__ S,
                                              const int* __restrict__ rowptr,
                                              int* __restrict__ cols,
                                              float* __restrict__ vals) {
  int lane = threadIdx.x & 63;
  int m = blockIdx.x * 4 + (threadIdx.x >> 6);
  int base = rowptr[m];
  for (int n0 = 0; n0 < N; n0 += 64) {
    int n = n0 + lane;
    float v = (n < N) ? S[m * N + n] : 0.f;
    bool nz = (v != 0.f);
    unsigned long long mask = __ballot(nz);
    int pos = base + (int)__popcll(mask & ((1ull << lane) - 1ull));
    if (nz && pos < CSR_CAP) { cols[pos] = n; vals[pos] = v; }
    base += (int)__popcll(mask);
  }
}

// ---------------- inputs transpose: (B,T,N) -> Xt[t][n*64+b] fp32 ----------

__global__ __launch_bounds__(256) void k_xt(const float* __restrict__ inp,
                                            float* __restrict__ xT) {
  __shared__ float tile[64][65];
  const int t  = blockIdx.y;
  const int n0 = blockIdx.x * 64;
  const int lx = threadIdx.x & 63;
  const int ly = threadIdx.x >> 6;
  for (int bb = ly; bb < 64; bb += 4) {
    int n = n0 + lx;
    tile[bb][lx] = (n < N) ? inp[(bb * T + t) * N + n] : 0.f;
  }
  __syncthreads();
  for (int nn = ly; nn < 64; nn += 4) {
    int n = n0 + nn;
    if (n < N) xT[((size_t)t * N + n) * 64 + lx] = tile[lx][nn];
  }
}

// ---------------- scalar Chebyshev chain (fp32, all timesteps) -------------
// 256-thr blocks (4 nodes each). m made wave-uniform via readfirstlane so
// rowptr/cols/vals go down the scalar (s_load) path.

__global__ __launch_bounds__(256) void k_sspmv(const int* __restrict__ rowptr,
                                               const int* __restrict__ cols,
                                               const float* __restrict__ vals,
                                               const float* __restrict__ in,
                                               const float* __restrict__ sub,
                                               float* __restrict__ out, int cheb) {
  const int wv = __builtin_amdgcn_readfirstlane(threadIdx.x >> 6);
  const int m = blockIdx.x * 4 + wv;
  const int b = threadIdx.x & 63;
  const size_t toff = (size_t)blockIdx.y * R;
  float acc = 0.f;
  const int s = rowptr[m], e = rowptr[m + 1];
  for (int j = s; j < e; ++j)
    acc = fmaf(vals[j], in[toff + cols[j] * 64 + b], acc);
  if (cheb) acc = 2.f * acc - sub[toff + m * 64 + b];
  out[toff + m * 64 + b] = acc;
}

// ---------------- W transpose+reorder -> Wt[o][256] bf16 -------------------
// kp<192: original row ((kp&63)+1)*3 + (kp>>6);  192..194: row kp-192; else 0.

__global__ __launch_bounds__(256) void k_wprep(
    const float* __restrict__ w0, const float* __restrict__ w1,
    const float* __restrict__ w2, const float* __restrict__ w3,
    u16* __restrict__ o0, u16* __restrict__ o1,
    u16* __restrict__ o2, u16* __restrict__ o3) {
  const float* W; u16* O; int ncol;
  switch (blockIdx.y) {
    case 0:  W = w0; O = o0; ncol = 128; break;
    case 1:  W = w1; O = o1; ncol = 64;  break;
    case 2:  W = w2; O = o2; ncol = 128; break;
    default: W = w3; O = o3; ncol = 64;  break;
  }
  int idx = blockIdx.x * 256 + threadIdx.x;
  if (idx >= ncol * RS) return;
  int o = idx / RS, kp = idx - o * RS;
  float v = 0.f;
  if (kp < 192)      v = W[(((kp & 63) + 1) * 3 + (kp >> 6)) * ncol + o];
  else if (kp < 195) v = W[(kp - 192) * ncol + o];
  O[idx] = f2bf(v);
}

// ---------------- zero seg0 of A1 (initial h = 0) --------------------------

__global__ __launch_bounds__(256) void k_zseg(u16* __restrict__ A) {
  int idx = blockIdx.x * 256 + threadIdx.x;     // 512k threads
  int r = idx >> 3, q = idx & 7;
  bf16x8 z = {0, 0, 0, 0, 0, 0, 0, 0};
  *(bf16x8*)(A + (size_t)r * RS + q * 8) = z;
}

// ---------------- bf16 diffusion spmv: seg1 = S @ seg0, XCD-pinned ---------
// grid (8, 250), 256 thr = 4 waves. blockIdx.x = chunk == XCD (x-major RR).
// Wave = ONE node m, made wave-uniform via readfirstlane: rowptr/cols/vals
// become SGPR s_loads (1 vector VMEM per nnz instead of 3; data-load address
// is SGPR-base + VGPR-lane-offset). Lane l: batch b = chunk*8 + (l>>3),
// 8 cols at cg = (l&7)*8. 8-wide unroll (r9-proven). Values identical ->
// bit-exact. xmode: 1 -> write scalar cols 192..194 from xs*; 2 -> zeros.

__global__ __launch_bounds__(256) void k_spv(
    const int* __restrict__ rowptr, const int* __restrict__ cols,
    const float* __restrict__ vals, u16* __restrict__ A,
    const float* __restrict__ xs0, const float* __restrict__ xs1,
    const float* __restrict__ xs2,
    u16* __restrict__ scA, u16* __restrict__ scB, int xmode) {
  const int chunk = blockIdx.x;
  const int wv = __builtin_amdgcn_readfirstlane(threadIdx.x >> 6);
  const int m = blockIdx.y * 4 + wv;
  const int l = threadIdx.x & 63;
  const int b = chunk * 8 + (l >> 3);
  const int cg = (l & 7) * 8;
  const int s = rowptr[m], e = rowptr[m + 1];
  const u16* in = A;                            // seg0

  float acc[8];
#pragma unroll
  for (int i = 0; i < 8; ++i) acc[i] = 0.f;

  int j = s;
  for (; j + 7 < e; j += 8) {
    float vv[8]; bf16x8 qq[8];
#pragma unroll
    for (int u8 = 0; u8 < 8; ++u8) {
      vv[u8] = vals[j + u8];
      qq[u8] = *(const bf16x8*)(in + ((size_t)cols[j + u8] * 64 + b) * RS + cg);
    }
#pragma unroll
    for (int i = 0; i < 8; ++i) {
      float a = acc[i];
#pragma unroll
      for (int u8 = 0; u8 < 8; ++u8) a = fmaf(vv[u8], bf2f((u16)qq[u8][i]), a);
      acc[i] = a;
    }
  }
  for (; j + 3 < e; j += 4) {
    const float v0 = vals[j],     v1 = vals[j + 1];
    const float v2 = vals[j + 2], v3 = vals[j + 3];
    bf16x8 q0 = *(const bf16x8*)(in + ((size_t)cols[j]     * 64 + b) * RS + cg);
    bf16x8 q1 = *(const bf16x8*)(in + ((size_t)cols[j + 1] * 64 + b) * RS + cg);
    bf16x8 q2 = *(const bf16x8*)(in + ((size_t)cols[j + 2] * 64 + b) * RS + cg);
    bf16x8 q3 = *(const bf16x8*)(in + ((size_t)cols[j + 3] * 64 + b) * RS + cg);
#pragma unroll
    for (int i = 0; i < 8; ++i)
      acc[i] = fmaf(v3, bf2f((u16)q3[i]),
               fmaf(v2, bf2f((u16)q2[i]),
               fmaf(v1, bf2f((u16)q1[i]),
               fmaf(v0, bf2f((u16)q0[i]), acc[i]))));
  }
  for (; j < e; ++j) {
    const float v = vals[j];
    bf16x8 q = *(const bf16x8*)(in + ((size_t)cols[j] * 64 + b) * RS + cg);
#pragma unroll
    for (int i = 0; i < 8; ++i) acc[i] = fmaf(v, bf2f((u16)q[i]), acc[i]);
  }

  const size_t ro = ((size_t)m * 64 + b) * RS + 64 + cg;   // seg1
  bf16x8 o;
#pragma unroll
  for (int i = 0; i < 8; ++i) o[i] = (short)f2bf(acc[i]);
  *(bf16x8*)(A + ro) = o;

  if (xmode && (l & 7) == 0) {
    const int r = m * 64 + b;
    u16 s0v = 0, s1v = 0, s2v = 0;
    if (xmode == 1) { s0v = f2bf(xs0[r]); s1v = f2bf(xs1[r]); s2v = f2bf(xs2[r]); }
    const size_t o2 = (size_t)r * RS + 192;
    scA[o2] = s0v; scA[o2 + 1] = s1v; scA[o2 + 2] = s2v;
    scB[o2] = s0v; scB[o2 + 1] = s1v; scB[o2 + 2] = s2v;
  }
}

// ---------------- bf16 diffusion spmv: seg2 = 2*(S @ seg1) - seg0 ----------
// Same scalarized shape; reads seg1, Chebyshev vs seg0, writes seg2.

__global__ __launch_bounds__(256) void k_spv2(
    const int* __restrict__ rowptr, const int* __restrict__ cols,
    const float* __restrict__ vals, u16* __restrict__ A) {
  const int chunk = blockIdx.x;
  const int wv = __builtin_amdgcn_readfirstlane(threadIdx.x >> 6);
  const int m = blockIdx.y * 4 + wv;
  const int l = threadIdx.x & 63;
  const int b = chunk * 8 + (l >> 3);
  const int cg = (l & 7) * 8;
  const int s = rowptr[m], e = rowptr[m + 1];
  const u16* in = A + 64;                       // seg1

  float acc[8];
#pragma unroll
  for (int i = 0; i < 8; ++i) acc[i] = 0.f;

  int j = s;
  for (; j + 7 < e; j += 8) {
    float vv[8]; bf16x8 qq[8];
#pragma unroll
    for (int u8 = 0; u8 < 8; ++u8) {
      vv[u8] = vals[j + u8];
      qq[u8] = *(const bf16x8*)(in + ((size_t)cols[j + u8] * 64 + b) * RS + cg);
    }
#pragma unroll
    for (int i = 0; i < 8; ++i) {
      float a = acc[i];
#pragma unroll
      for (int u8 = 0; u8 < 8; ++u8) a = fmaf(vv[u8], bf2f((u16)qq[u8][i]), a);
      acc[i] = a;
    }
  }
  for (; j + 3 < e; j += 4) {
    const float v0 = vals[j],     v1 = vals[j + 1];
    const float v2 = vals[j + 2], v3 = vals[j + 3];
    bf16x8 q0 = *(const bf16x8*)(in + ((size_t)cols[j]     * 64 + b) * RS + cg);
    bf16x8 q1 = *(const bf16x8*)(in + ((size_t)cols[j + 1] * 64 + b) * RS + cg);
    bf16x8 q2 = *(const bf16x8*)(in + ((size_t)cols[j + 2] * 64 + b) * RS + cg);
    bf16x8 q3 = *(const bf16x8*)(in + ((size_t)cols[j + 3] * 64 + b) * RS + cg);
#pragma unroll
    for (int i = 0; i < 8; ++i)
      acc[i] = fmaf(v3, bf2f((u16)q3[i]),
               fmaf(v2, bf2f((u16)q2[i]),
               fmaf(v1, bf2f((u16)q1[i]),
               fmaf(v0, bf2f((u16)q0[i]), acc[i]))));
  }
  for (; j < e; ++j) {
    const float v = vals[j];
    bf16x8 q = *(const bf16x8*)(in + ((size_t)cols[j] * 64 + b) * RS + cg);
#pragma unroll
    for (int i = 0; i < 8; ++i) acc[i] = fmaf(v, bf2f((u16)q[i]), acc[i]);
  }

  const size_t rb = ((size_t)m * 64 + b) * RS + cg;
  bf16x8 sb = *(const bf16x8*)(A + rb);         // seg0 (sub)
  bf16x8 o;
#pragma unroll
  for (int i = 0; i < 8; ++i) o[i] = (short)f2bf(2.f * acc[i] - bf2f((u16)sb[i]));
  *(bf16x8*)(A + rb + 128) = o;                 // seg2
}

// ---------------- MFMA GEMM, XCD-pinned, K-halved LDS, 256-thr -------------
// (r13/r14-proven: 100% occupancy, bit-exact.) ks 0..6 ascending; ks=7
// dropped (W rows 224..255 == 0). W staged per K-half into 16KB LDS,
// XOR-swizzled (chunk ^= row&7). EPI0: grid (8,125,2), z = col-half (ob).
// EPI1: grid (8,125), ob=0.

template <int EPI>
__global__ __launch_bounds__(256) void k_mg2(
    const u16* __restrict__ A, const u16* __restrict__ Wt,
    const float* __restrict__ bias,
    u16* __restrict__ outA, u16* __restrict__ ubuf,
    float* __restrict__ hbuf) {
  __shared__ u16 Wl[64 * 128];                 // 16 KB, one K-half
  const int chunk = blockIdx.x;
  const int ob = EPI ? 0 : blockIdx.z * 64;
  const int w  = threadIdx.x >> 6;
  const int n0 = blockIdx.y * 8;
  const int l  = threadIdx.x & 63;
  const int lr = l & 15, lk = l >> 4;
  const int bphys = chunk * 8 + (lr & 7);
  const int tc = threadIdx.x & 15, tr0 = threadIdx.x >> 4;   // 16 rows x 16 chunks

  const int nA = n0 + 2 * w + (lr >> 3);
  const size_t ra = ((size_t)nA * 64 + bphys) * RS + lk * 8;

  f32x4 acc[4];
#pragma unroll
  for (int cb = 0; cb < 4; ++cb) acc[cb] = (f32x4){0.f, 0.f, 0.f, 0.f};

  // ---- K-half 0: k 0..127 (16 chunks/row) ----
  for (int r = tr0; r < 64; r += 16)
    *(bf16x8*)(Wl + r * 128 + ((tc ^ (r & 7)) * 8)) =
        *(const bf16x8*)(Wt + (size_t)(ob + r) * RS + tc * 8);
  __syncthreads();
#pragma unroll
  for (int ks = 0; ks < 4; ++ks) {
    bf16x8 a = *(const bf16x8*)(A + ra + ks * 32);
#pragma unroll
    for (int cb = 0; cb < 4; ++cb) {
      const int wrow = cb * 16 + lr;
      bf16x8 bb = *(const bf16x8*)(Wl + wrow * 128 +
                                   (((ks * 4 + lk) ^ (wrow & 7)) * 8));
      acc[cb] = __builtin_amdgcn_mfma_f32_16x16x32_bf16(a, bb, acc[cb], 0, 0, 0);
    }
  }
  __syncthreads();
  // ---- K-half 1: k 128..223 (12 chunks/row) ----
  if (tc < 12)
    for (int r = tr0; r < 64; r += 16)
      *(bf16x8*)(Wl + r * 128 + ((tc ^ (r & 7)) * 8)) =
          *(const bf16x8*)(Wt + (size_t)(ob + r) * RS + 128 + tc * 8);
  __syncthreads();
#pragma unroll
  for (int ks = 4; ks < 7; ++ks) {
    bf16x8 a = *(const bf16x8*)(A + ra + ks * 32);
#pragma unroll
    for (int cb = 0; cb < 4; ++cb) {
      const int wrow = cb * 16 + lr;
      bf16x8 bb = *(const bf16x8*)(Wl + wrow * 128 +
                                   ((((ks - 4) * 4 + lk) ^ (wrow & 7)) * 8));
      acc[cb] = __builtin_amdgcn_mfma_f32_16x16x32_bf16(a, bb, acc[cb], 0, 0, 0);
    }
  }

  // ---- epilogue ----
#pragma unroll
  for (int cb = 0; cb < 4; ++cb) {
    const int col = ob + cb * 16 + lr;
    const float bs = bias[col];
#pragma unroll
    for (int j4 = 0; j4 < 4; ++j4) {
      const int trow = lk * 4 + j4;
      const int prow = (n0 + 2 * w + (trow >> 3)) * 64 + chunk * 8 + (trow & 7);
      const float v = acc[cb][j4] + bs;
      if (EPI == 0) {
        const float sig = 1.f / (1.f + expf(-v));
        if (col < 64)
          outA[(size_t)prow * RS + col] = f2bf(sig * hbuf[(size_t)prow * 64 + col]);
        else
          ubuf[(size_t)prow * 64 + (col - 64)] = f2bf(sig);
      } else {
        const float cc = tanhf(v);
        const size_t i64 = (size_t)prow * 64 + col;
        const float u = bf2f(ubuf[i64]);
        const float hn = u * hbuf[i64] + (1.f - u) * cc;
        hbuf[i64] = hn;
        outA[(size_t)prow * RS + col] = f2bf(hn);
      }
    }
  }
}

// ---------------- final projection ----------------

__global__ __launch_bounds__(256) void k_proj(const float* __restrict__ h,
                                              const float* __restrict__ Wp,
                                              const float* __restrict__ bp,
                                              float* __restrict__ out) {
  int lane = threadIdx.x & 63;
  int r = blockIdx.x * 4 + (threadIdx.x >> 6);
  float p = h[(size_t)r * 64 + lane] * Wp[lane];
  for (int off = 32; off; off >>= 1) p += __shfl_down(p, off, 64);
  if (lane == 0) {
    int n = r >> 6, b = r & 63;
    out[b * N + n] = p + bp[0];
  }
}

// ---------------- host launch ----------------

extern "C" void kernel_launch(void* const* d_in, const int* in_sizes, int n_in,
                              void* d_out, int out_size, void* d_ws, size_t ws_size,
                              hipStream_t stream) {
  const float* inp  = (const float*)d_in[0];
  const float* S    = (const float*)d_in[1];
  const float* eWru = (const float*)d_in[2];
  const float* ebru = (const float*)d_in[3];
  const float* eWc  = (const float*)d_in[4];
  const float* ebc  = (const float*)d_in[5];
  const float* dWru = (const float*)d_in[6];
  const float* dbru = (const float*)d_in[7];
  const float* dWc  = (const float*)d_in[8];
  const float* dbc  = (const float*)d_in[9];
  const float* Wp   = (const float*)d_in[10];
  const float* bp   = (const float*)d_in[11];
  float* out = (float*)d_out;

  char* p = (char*)d_ws;
  auto alloc = [&](size_t bytes) { void* q = p; p += (bytes + 255) & ~(size_t)255; return q; };
  u16*   A1    = (u16*)alloc((size_t)R * RS * 2);
  u16*   A2    = (u16*)alloc((size_t)R * RS * 2);
  float* hbuf  = (float*)alloc((size_t)R * 64 * 4);
  u16*   ubuf  = (u16*)alloc((size_t)R * 64 * 2);
  float* Xt    = (float*)alloc((size_t)T * R * 4);
  float* x1s   = (float*)alloc((size_t)T * R * 4);
  float* x2s   = (float*)alloc((size_t)T * R * 4);
  u16*   WtRUe = (u16*)alloc(128 * RS * 2);
  u16*   WtCe  = (u16*)alloc(64 * RS * 2);
  u16*   WtRUd = (u16*)alloc(128 * RS * 2);
  u16*   WtCd  = (u16*)alloc(64 * RS * 2);
  int*   rowptr = (int*)alloc(1024 * 4);
  int*   cols   = (int*)alloc(CSR_CAP * 4);
  float* vals   = (float*)alloc(CSR_CAP * 4);

  // initial h=0 lives in A1 seg0 (bf16) and hbuf (fp32). Scalar pad cols
  // 195..223 multiply zeroed Wt rows; cols 224..255 untouched (ks<=6).
  k_zseg<<<2000, 256, 0, stream>>>(A1);
  hipMemsetAsync(hbuf, 0, (size_t)R * 64 * 4, stream);

  // prep: CSR, input transpose, scalar chains, transposed weights
  k_count<<<250, 256, 0, stream>>>(S, rowptr);
  k_scan<<<1, 1024, 0, stream>>>(rowptr);
  k_fill<<<250, 256, 0, stream>>>(S, rowptr, cols, vals);
  k_xt<<<dim3(16, T), 256, 0, stream>>>(inp, Xt);
  k_sspmv<<<dim3(250, T), 256, 0, stream>>>(rowptr, cols, vals, Xt, nullptr, x1s, 0);
  k_sspmv<<<dim3(250, T), 256, 0, stream>>>(rowptr, cols, vals, x1s, Xt, x2s, 1);
  k_wprep<<<dim3(128, 4), 256, 0, stream>>>(eWru, eWc, dWru, dWc,
                                            WtRUe, WtCe, WtRUd, WtCd);

  dim3 gsp(8, 250);

  auto cell = [&](int t, const u16* Wru, const float* bru,
                  const u16* Wc, const float* bc) {
    const int xmode = (t >= 0) ? 1 : 2;
    const float* xs0 = (t >= 0) ? Xt  + (size_t)t * R : Xt;
    const float* xs1 = (t >= 0) ? x1s + (size_t)t * R : Xt;
    const float* xs2 = (t >= 0) ? x2s + (size_t)t * R : Xt;
    // gconv1 on A1 (seg0 = h): x1 = S@h, x2 = 2*S@x1 - h
    k_spv<<<gsp, 256, 0, stream>>>(rowptr, cols, vals, A1,
                                   xs0, xs1, xs2, A1, A2, xmode);
    k_spv2<<<gsp, 256, 0, stream>>>(rowptr, cols, vals, A1);
    k_mg2<0><<<dim3(8, 125, 2), 256, 0, stream>>>(A1, Wru, bru, A2, ubuf, hbuf);
    // gconv2 on A2 (seg0 = r.*h)
    k_spv<<<gsp, 256, 0, stream>>>(rowptr, cols, vals, A2,
                                   nullptr, nullptr, nullptr,
                                   nullptr, nullptr, 0);
    k_spv2<<<gsp, 256, 0, stream>>>(rowptr, cols, vals, A2);
    k_mg2<1><<<dim3(8, 125), 256, 0, stream>>>(A2, Wc, bc, A1, ubuf, hbuf);
  };

  for (int t = 0; t < T; ++t) cell(t, WtRUe, ebru, WtCe, ebc);  // encoder
  cell(-1, WtRUd, dbru, WtCd, dbc);                             // decoder

  k_proj<<<16000, 256, 0, stream>>>(hbuf, Wp, bp, out);
  (void)in_sizes; (void)n_in; (void)out_size; (void)ws_size;
}